// Round 3
// baseline (239.085 us; speedup 1.0000x reference)
//
#include <hip/hip_runtime.h>
#include <hip/hip_bf16.h>

// Problem dims
#define BB 4
#define SS 1024
#define EE 192
#define HH 64
// D = 3 (head dim)

constexpr int BH = BB * HH;  // 256

// ws layout (in floats)
constexpr size_t OFF_WQR = 0;                         // E*E rotated+scaled Wq
constexpr size_t OFF_WKR = OFF_WQR + (size_t)EE*EE;   // E*E rotated Wk
constexpr size_t OFF_Q   = OFF_WKR + (size_t)EE*EE;   // (B*H, S, 4) padded
constexpr size_t SZ_Q    = (size_t)BH*SS*4;
constexpr size_t OFF_KV  = OFF_Q + SZ_Q;              // (B*H, S, 8): k0 k1 k2 _ v0 v1 v2 _
constexpr size_t SZ_KV   = (size_t)BH*SS*8;
constexpr size_t OFF_AO  = OFF_KV + SZ_KV;            // (B, S, E) attention output

static __device__ __forceinline__ float fast_exp2(float x) {
#if __has_builtin(__builtin_amdgcn_exp2f)
  return __builtin_amdgcn_exp2f(x);
#else
  return exp2f(x);
#endif
}
static __device__ __forceinline__ float fast_rcp(float x) {
#if __has_builtin(__builtin_amdgcn_rcpf)
  return __builtin_amdgcn_rcpf(x);
#else
  return 1.0f / x;
#endif
}

// Fold per-head 3x3 rotation into Wq and Wk (fp32, exact restructuring).
// WqR additionally carries log2(e)/sqrt(3) so attention exp is a single v_exp_f32.
__global__ __launch_bounds__(256) void fold_rot_k(
    const float* __restrict__ Wq, const float* __restrict__ Wk,
    const float* __restrict__ rot, float* __restrict__ WqR, float* __restrict__ WkR)
{
  int t = blockIdx.x * 256 + threadIdx.x;
  if (t >= 2 * EE * EE) return;
  int mat = t / (EE * EE);
  int idx = t % (EE * EE);
  int op = idx / EE, e = idx % EE;      // op = h*3 + e'
  int h = op / 3, ep = op - h * 3;
  const float* W = mat ? Wk : Wq;
  float acc = 0.f;
#pragma unroll
  for (int d = 0; d < 3; ++d)
    acc += rot[h * 9 + d * 3 + ep] * W[(h * 3 + d) * EE + e];
  float scale = mat ? 1.0f : 0.8329876360019913f;  // log2(e)/sqrt(3)
  (mat ? WkR : WqR)[op * EE + e] = acc * scale;
}

// QKV projection GEMM: (4096 x 192) @ W^T for W in {WqR, WkR, Wv}.
// grid = (9 col-tiles, 64 row-tiles); tiles 0-2 -> Q, 3-5 -> K, 6-8 -> V.
// LDS tiles stored k-major (transposed) with pad 68 for aligned ds_read_b128.
__global__ __launch_bounds__(256) void gemm_qkv_k(
    const float* __restrict__ x, const float* __restrict__ WqR,
    const float* __restrict__ WkR, const float* __restrict__ Wv,
    float* __restrict__ Q, float* __restrict__ KV)
{
  __shared__ __align__(16) float xs[64][68];
  __shared__ __align__(16) float wsm[64][68];
  int bx = blockIdx.x;   // 0..8
  int by = blockIdx.y;   // 0..63
  int t = threadIdx.x;
  int sel = bx / 3;
  const float* W = (sel == 0) ? WqR : (sel == 1 ? WkR : Wv);
  int colBase = (bx % 3) * 64;
  int rowBase = by * 64;
  int lrow = t >> 2, lq = t & 3;
  int tr = t & 15, tc = t >> 4;
  float acc[4][4] = {};

  for (int kk = 0; kk < 3; ++kk) {
    const float* xg = x + (size_t)(rowBase + lrow) * EE + kk * 64;
    const float* wg = W + (size_t)(colBase + lrow) * EE + kk * 64;
    float4 xv[4], wv[4];
#pragma unroll
    for (int i = 0; i < 4; ++i) {
      xv[i] = ((const float4*)xg)[lq + 4 * i];
      wv[i] = ((const float4*)wg)[lq + 4 * i];
    }
    __syncthreads();
#pragma unroll
    for (int i = 0; i < 4; ++i) {
      int k0 = (lq + 4 * i) * 4;
      xs[k0 + 0][lrow] = xv[i].x; xs[k0 + 1][lrow] = xv[i].y;
      xs[k0 + 2][lrow] = xv[i].z; xs[k0 + 3][lrow] = xv[i].w;
      wsm[k0 + 0][lrow] = wv[i].x; wsm[k0 + 1][lrow] = wv[i].y;
      wsm[k0 + 2][lrow] = wv[i].z; wsm[k0 + 3][lrow] = wv[i].w;
    }
    __syncthreads();
#pragma unroll 8
    for (int k = 0; k < 64; ++k) {
      float4 a = *(const float4*)&xs[k][tr * 4];
      float4 bv = *(const float4*)&wsm[k][tc * 4];
      acc[0][0] += a.x * bv.x; acc[0][1] += a.x * bv.y; acc[0][2] += a.x * bv.z; acc[0][3] += a.x * bv.w;
      acc[1][0] += a.y * bv.x; acc[1][1] += a.y * bv.y; acc[1][2] += a.y * bv.z; acc[1][3] += a.y * bv.w;
      acc[2][0] += a.z * bv.x; acc[2][1] += a.z * bv.y; acc[2][2] += a.z * bv.z; acc[2][3] += a.z * bv.w;
      acc[3][0] += a.w * bv.x; acc[3][1] += a.w * bv.y; acc[3][2] += a.w * bv.z; acc[3][3] += a.w * bv.w;
    }
  }

#pragma unroll
  for (int i = 0; i < 4; ++i) {
    int r = rowBase + tr * 4 + i;
    int b = r >> 10, s = r & (SS - 1);
#pragma unroll
    for (int j = 0; j < 4; ++j) {
      int o = colBase + tc * 4 + j;
      int h = o / 3, d = o - h * 3;
      size_t base = ((size_t)(b * HH + h) * SS + s);
      if (sel == 0)      Q[base * 4 + d] = acc[i][j];
      else if (sel == 1) KV[base * 8 + d] = acc[i][j];
      else               KV[base * 8 + 4 + d] = acc[i][j];
    }
  }
}

// Attention: k_j/v_j are wave-uniform -> load KV rows via SCALAR loads
// (uniform address => s_load_dwordx8 from K$/L2), zero LDS, zero VALU spent
// on data movement. 1024 blocks (4 row-parts per (b,h)), 1 row/thread,
// j-loop unrolled x4 with independent accumulator chains.
// Part-major block index keeps same-head blocks on the same XCD.
__global__ __launch_bounds__(256) void attn_k(
    const float* __restrict__ Qw, const float* __restrict__ KVw, float* __restrict__ AO)
{
  int bh = blockIdx.x & 255;      // part-major: same head every 256 blocks
  int part = blockIdx.x >> 8;
  int b = bh >> 6, h = bh & 63;
  const float* __restrict__ kvg =
      (const float*)__builtin_assume_aligned(KVw + (size_t)bh * (SS * 8), 32);

  int r = part * 256 + threadIdx.x;
  const float* qg = Qw + (size_t)bh * (SS * 4) + (size_t)r * 4;
  float4 qa = *(const float4*)qg;
  float q0 = qa.x, q1 = qa.y, q2 = qa.z;

  float l[4] = {0.f, 0.f, 0.f, 0.f};
  float o0[4] = {}, o1[4] = {}, o2[4] = {};

  for (int j = 0; j < SS; j += 4) {
#pragma unroll
    for (int u = 0; u < 4; ++u) {
      const float* kr = kvg + (size_t)(j + u) * 8;  // uniform address
      float k0 = kr[0], k1 = kr[1], k2 = kr[2];
      float v0 = kr[4], v1 = kr[5], v2 = kr[6];
      float s = q0 * k0 + q1 * k1 + q2 * k2;
      float p = fast_exp2(s);   // exp(qk/sqrt(3)); log2e/sqrt3 folded into Q
      l[u] += p;
      o0[u] += p * v0; o1[u] += p * v1; o2[u] += p * v2;
    }
  }

  float lt = (l[0] + l[1]) + (l[2] + l[3]);
  float a0 = (o0[0] + o0[1]) + (o0[2] + o0[3]);
  float a1 = (o1[0] + o1[1]) + (o1[2] + o1[3]);
  float a2 = (o2[0] + o2[1]) + (o2[2] + o2[3]);
  float inv = fast_rcp(lt);
  float* dst = AO + ((size_t)(b * SS + r)) * EE + h * 3;
  dst[0] = a0 * inv; dst[1] = a1 * inv; dst[2] = a2 * inv;
}

// Output projection: AO (4096 x 192) @ Wo^T -> out. grid = (3, 64).
__global__ __launch_bounds__(256) void gemm_out_k(
    const float* __restrict__ x, const float* __restrict__ Wo, float* __restrict__ out)
{
  __shared__ __align__(16) float xs[64][68];
  __shared__ __align__(16) float wsm[64][68];
  int bx = blockIdx.x;   // 0..2
  int by = blockIdx.y;   // 0..63
  int t = threadIdx.x;
  int colBase = bx * 64;
  int rowBase = by * 64;
  int lrow = t >> 2, lq = t & 3;
  int tr = t & 15, tc = t >> 4;
  float acc[4][4] = {};

  for (int kk = 0; kk < 3; ++kk) {
    const float* xg = x + (size_t)(rowBase + lrow) * EE + kk * 64;
    const float* wg = Wo + (size_t)(colBase + lrow) * EE + kk * 64;
    float4 xv[4], wv[4];
#pragma unroll
    for (int i = 0; i < 4; ++i) {
      xv[i] = ((const float4*)xg)[lq + 4 * i];
      wv[i] = ((const float4*)wg)[lq + 4 * i];
    }
    __syncthreads();
#pragma unroll
    for (int i = 0; i < 4; ++i) {
      int k0 = (lq + 4 * i) * 4;
      xs[k0 + 0][lrow] = xv[i].x; xs[k0 + 1][lrow] = xv[i].y;
      xs[k0 + 2][lrow] = xv[i].z; xs[k0 + 3][lrow] = xv[i].w;
      wsm[k0 + 0][lrow] = wv[i].x; wsm[k0 + 1][lrow] = wv[i].y;
      wsm[k0 + 2][lrow] = wv[i].z; wsm[k0 + 3][lrow] = wv[i].w;
    }
    __syncthreads();
#pragma unroll 8
    for (int k = 0; k < 64; ++k) {
      float4 a = *(const float4*)&xs[k][tr * 4];
      float4 bv = *(const float4*)&wsm[k][tc * 4];
      acc[0][0] += a.x * bv.x; acc[0][1] += a.x * bv.y; acc[0][2] += a.x * bv.z; acc[0][3] += a.x * bv.w;
      acc[1][0] += a.y * bv.x; acc[1][1] += a.y * bv.y; acc[1][2] += a.y * bv.z; acc[1][3] += a.y * bv.w;
      acc[2][0] += a.z * bv.x; acc[2][1] += a.z * bv.y; acc[2][2] += a.z * bv.z; acc[2][3] += a.z * bv.w;
      acc[3][0] += a.w * bv.x; acc[3][1] += a.w * bv.y; acc[3][2] += a.w * bv.z; acc[3][3] += a.w * bv.w;
    }
  }

#pragma unroll
  for (int i = 0; i < 4; ++i) {
    int r = rowBase + tr * 4 + i;
#pragma unroll
    for (int j = 0; j < 4; ++j) {
      int o = colBase + tc * 4 + j;
      out[(size_t)r * EE + o] = acc[i][j];
    }
  }
}

extern "C" void kernel_launch(void* const* d_in, const int* in_sizes, int n_in,
                              void* d_out, int out_size, void* d_ws, size_t ws_size,
                              hipStream_t stream) {
  const float* x   = (const float*)d_in[0];
  const float* Wq  = (const float*)d_in[1];
  const float* Wk  = (const float*)d_in[2];
  const float* Wv  = (const float*)d_in[3];
  const float* Wo  = (const float*)d_in[4];
  const float* rot = (const float*)d_in[5];
  float* ws  = (float*)d_ws;
  float* WqR = ws + OFF_WQR;
  float* WkR = ws + OFF_WKR;
  float* Q   = ws + OFF_Q;
  float* KV  = ws + OFF_KV;
  float* AO  = ws + OFF_AO;
  float* out = (float*)d_out;

  fold_rot_k<<<dim3((2 * EE * EE + 255) / 256), 256, 0, stream>>>(Wq, Wk, rot, WqR, WkR);
  gemm_qkv_k<<<dim3(9, 64), 256, 0, stream>>>(x, WqR, WkR, Wv, Q, KV);
  attn_k<<<dim3(BH * 4), 256, 0, stream>>>(Q, KV, AO);
  gemm_out_k<<<dim3(3, 64), 256, 0, stream>>>(AO, Wo, out);
}

// Round 4
// 121.048 us; speedup vs baseline: 1.9751x; 1.9751x over previous
//
#include <hip/hip_runtime.h>
#include <hip/hip_bf16.h>

// Problem dims
#define BB 4
#define SS 1024
#define EE 192
#define HH 64
// D = 3 (head dim)

constexpr int BH = BB * HH;  // 256

// ws layout (in floats)
constexpr size_t OFF_WQR = 0;                         // E*E rotated+scaled Wq
constexpr size_t OFF_WKR = OFF_WQR + (size_t)EE*EE;   // E*E rotated Wk
constexpr size_t OFF_Q   = OFF_WKR + (size_t)EE*EE;   // (B*H, S, 4) padded
constexpr size_t SZ_Q    = (size_t)BH*SS*4;
constexpr size_t OFF_KV  = OFF_Q + SZ_Q;              // (B*H, S, 8): k0 k1 k2 _ v0 v1 v2 _
constexpr size_t SZ_KV   = (size_t)BH*SS*8;
constexpr size_t OFF_AO  = OFF_KV + SZ_KV;            // (B, S, E) attention output

static __device__ __forceinline__ float fast_exp2(float x) {
#if __has_builtin(__builtin_amdgcn_exp2f)
  return __builtin_amdgcn_exp2f(x);
#else
  return exp2f(x);
#endif
}
static __device__ __forceinline__ float fast_rcp(float x) {
#if __has_builtin(__builtin_amdgcn_rcpf)
  return __builtin_amdgcn_rcpf(x);
#else
  return 1.0f / x;
#endif
}

// Fold per-head 3x3 rotation into Wq and Wk (fp32, exact restructuring).
// WqR additionally carries log2(e)/sqrt(3) so attention exp is a single v_exp_f32.
__global__ __launch_bounds__(256) void fold_rot_k(
    const float* __restrict__ Wq, const float* __restrict__ Wk,
    const float* __restrict__ rot, float* __restrict__ WqR, float* __restrict__ WkR)
{
  int t = blockIdx.x * 256 + threadIdx.x;
  if (t >= 2 * EE * EE) return;
  int mat = t / (EE * EE);
  int idx = t % (EE * EE);
  int op = idx / EE, e = idx % EE;      // op = h*3 + e'
  int h = op / 3, ep = op - h * 3;
  const float* W = mat ? Wk : Wq;
  float acc = 0.f;
#pragma unroll
  for (int d = 0; d < 3; ++d)
    acc += rot[h * 9 + d * 3 + ep] * W[(h * 3 + d) * EE + e];
  float scale = mat ? 1.0f : 0.8329876360019913f;  // log2(e)/sqrt(3)
  (mat ? WkR : WqR)[op * EE + e] = acc * scale;
}

// QKV projection GEMM: (4096 x 192) @ W^T for W in {WqR, WkR, Wv}.
__global__ __launch_bounds__(256) void gemm_qkv_k(
    const float* __restrict__ x, const float* __restrict__ WqR,
    const float* __restrict__ WkR, const float* __restrict__ Wv,
    float* __restrict__ Q, float* __restrict__ KV)
{
  __shared__ __align__(16) float xs[64][68];
  __shared__ __align__(16) float wsm[64][68];
  int bx = blockIdx.x;   // 0..8
  int by = blockIdx.y;   // 0..63
  int t = threadIdx.x;
  int sel = bx / 3;
  const float* W = (sel == 0) ? WqR : (sel == 1 ? WkR : Wv);
  int colBase = (bx % 3) * 64;
  int rowBase = by * 64;
  int lrow = t >> 2, lq = t & 3;
  int tr = t & 15, tc = t >> 4;
  float acc[4][4] = {};

  for (int kk = 0; kk < 3; ++kk) {
    const float* xg = x + (size_t)(rowBase + lrow) * EE + kk * 64;
    const float* wg = W + (size_t)(colBase + lrow) * EE + kk * 64;
    float4 xv[4], wv[4];
#pragma unroll
    for (int i = 0; i < 4; ++i) {
      xv[i] = ((const float4*)xg)[lq + 4 * i];
      wv[i] = ((const float4*)wg)[lq + 4 * i];
    }
    __syncthreads();
#pragma unroll
    for (int i = 0; i < 4; ++i) {
      int k0 = (lq + 4 * i) * 4;
      xs[k0 + 0][lrow] = xv[i].x; xs[k0 + 1][lrow] = xv[i].y;
      xs[k0 + 2][lrow] = xv[i].z; xs[k0 + 3][lrow] = xv[i].w;
      wsm[k0 + 0][lrow] = wv[i].x; wsm[k0 + 1][lrow] = wv[i].y;
      wsm[k0 + 2][lrow] = wv[i].z; wsm[k0 + 3][lrow] = wv[i].w;
    }
    __syncthreads();
#pragma unroll 8
    for (int k = 0; k < 64; ++k) {
      float4 a = *(const float4*)&xs[k][tr * 4];
      float4 bv = *(const float4*)&wsm[k][tc * 4];
      acc[0][0] += a.x * bv.x; acc[0][1] += a.x * bv.y; acc[0][2] += a.x * bv.z; acc[0][3] += a.x * bv.w;
      acc[1][0] += a.y * bv.x; acc[1][1] += a.y * bv.y; acc[1][2] += a.y * bv.z; acc[1][3] += a.y * bv.w;
      acc[2][0] += a.z * bv.x; acc[2][1] += a.z * bv.y; acc[2][2] += a.z * bv.z; acc[2][3] += a.z * bv.w;
      acc[3][0] += a.w * bv.x; acc[3][1] += a.w * bv.y; acc[3][2] += a.w * bv.z; acc[3][3] += a.w * bv.w;
    }
  }

#pragma unroll
  for (int i = 0; i < 4; ++i) {
    int r = rowBase + tr * 4 + i;
    int b = r >> 10, s = r & (SS - 1);
#pragma unroll
    for (int j = 0; j < 4; ++j) {
      int o = colBase + tc * 4 + j;
      int h = o / 3, d = o - h * 3;
      size_t base = ((size_t)(b * HH + h) * SS + s);
      if (sel == 0)      Q[base * 4 + d] = acc[i][j];
      else if (sel == 1) KV[base * 8 + d] = acc[i][j];
      else               KV[base * 8 + 4 + d] = acc[i][j];
    }
  }
}

// Attention: block = (head, rowhalf) -> 512 blocks, 2 blocks/CU, 8 waves/CU.
// Within a block: 4 waves each take a 256-key chunk, all 512 rows at R=8
// rows/thread. KV broadcast-read from LDS (2x b128 per key per wave);
// per-wave partial (l, o) combined via LDS reduce (exp2 with no max pass ->
// partials are trivially additive), then normalize + write AO.
__global__ __launch_bounds__(256) void attn_k(
    const float* __restrict__ Qw, const float* __restrict__ KVw, float* __restrict__ AO)
{
  __shared__ __align__(16) float4 kv4[SS * 2];     // 32 KB: whole head's KV
  __shared__ __align__(16) float4 part[4][512];    // 32 KB: [wave][row] {l,o0,o1,o2}
  int bh = blockIdx.x & 255;       // rowhalf-major: same-head blocks 256 apart (same XCD)
  int rowhalf = blockIdx.x >> 8;
  int b = bh >> 6, h = bh & 63;

  const float4* kvg = (const float4*)(KVw + (size_t)bh * (SS * 8));
  for (int i = threadIdx.x; i < SS * 2; i += 256) kv4[i] = kvg[i];
  __syncthreads();

  int lane = threadIdx.x & 63, w = threadIdx.x >> 6;
  const float* qg = Qw + (size_t)bh * (SS * 4);
  int r0 = rowhalf * 512 + lane;

  float q0[8], q1[8], q2[8];
  float l[8] = {}, o0[8] = {}, o1[8] = {}, o2[8] = {};
#pragma unroll
  for (int i = 0; i < 8; ++i) {
    float4 qa = *(const float4*)&qg[(size_t)(r0 + i * 64) * 4];
    q0[i] = qa.x; q1[i] = qa.y; q2[i] = qa.z;
  }

  const float4* kp = &kv4[(size_t)w * 512];  // this wave's 256-key chunk
#pragma unroll 2
  for (int j = 0; j < 256; ++j) {
    float4 ka = kp[2 * j];
    float4 va = kp[2 * j + 1];
#pragma unroll
    for (int i = 0; i < 8; ++i) {
      float s = q0[i] * ka.x + q1[i] * ka.y + q2[i] * ka.z;
      float p = fast_exp2(s);   // exp(qk/sqrt(3)); log2e/sqrt3 folded into Q
      l[i] += p;
      o0[i] += p * va.x; o1[i] += p * va.y; o2[i] += p * va.z;
    }
  }

#pragma unroll
  for (int i = 0; i < 8; ++i)
    part[w][i * 64 + lane] = make_float4(l[i], o0[i], o1[i], o2[i]);
  __syncthreads();

  // 512 rows / 256 threads = 2 rows per thread
#pragma unroll
  for (int rr = 0; rr < 2; ++rr) {
    int row = threadIdx.x * 2 + rr;
    float4 p0 = part[0][row], p1 = part[1][row], p2 = part[2][row], p3 = part[3][row];
    float lt = (p0.x + p1.x) + (p2.x + p3.x);
    float a0 = (p0.y + p1.y) + (p2.y + p3.y);
    float a1 = (p0.z + p1.z) + (p2.z + p3.z);
    float a2 = (p0.w + p1.w) + (p2.w + p3.w);
    float inv = fast_rcp(lt);
    int r = rowhalf * 512 + row;
    float* dst = AO + ((size_t)(b * SS + r)) * EE + h * 3;
    dst[0] = a0 * inv; dst[1] = a1 * inv; dst[2] = a2 * inv;
  }
}

// Output projection: AO (4096 x 192) @ Wo^T -> out. grid = (3, 64).
__global__ __launch_bounds__(256) void gemm_out_k(
    const float* __restrict__ x, const float* __restrict__ Wo, float* __restrict__ out)
{
  __shared__ __align__(16) float xs[64][68];
  __shared__ __align__(16) float wsm[64][68];
  int bx = blockIdx.x;   // 0..2
  int by = blockIdx.y;   // 0..63
  int t = threadIdx.x;
  int colBase = bx * 64;
  int rowBase = by * 64;
  int lrow = t >> 2, lq = t & 3;
  int tr = t & 15, tc = t >> 4;
  float acc[4][4] = {};

  for (int kk = 0; kk < 3; ++kk) {
    const float* xg = x + (size_t)(rowBase + lrow) * EE + kk * 64;
    const float* wg = Wo + (size_t)(colBase + lrow) * EE + kk * 64;
    float4 xv[4], wv[4];
#pragma unroll
    for (int i = 0; i < 4; ++i) {
      xv[i] = ((const float4*)xg)[lq + 4 * i];
      wv[i] = ((const float4*)wg)[lq + 4 * i];
    }
    __syncthreads();
#pragma unroll
    for (int i = 0; i < 4; ++i) {
      int k0 = (lq + 4 * i) * 4;
      xs[k0 + 0][lrow] = xv[i].x; xs[k0 + 1][lrow] = xv[i].y;
      xs[k0 + 2][lrow] = xv[i].z; xs[k0 + 3][lrow] = xv[i].w;
      wsm[k0 + 0][lrow] = wv[i].x; wsm[k0 + 1][lrow] = wv[i].y;
      wsm[k0 + 2][lrow] = wv[i].z; wsm[k0 + 3][lrow] = wv[i].w;
    }
    __syncthreads();
#pragma unroll 8
    for (int k = 0; k < 64; ++k) {
      float4 a = *(const float4*)&xs[k][tr * 4];
      float4 bv = *(const float4*)&wsm[k][tc * 4];
      acc[0][0] += a.x * bv.x; acc[0][1] += a.x * bv.y; acc[0][2] += a.x * bv.z; acc[0][3] += a.x * bv.w;
      acc[1][0] += a.y * bv.x; acc[1][1] += a.y * bv.y; acc[1][2] += a.y * bv.z; acc[1][3] += a.y * bv.w;
      acc[2][0] += a.z * bv.x; acc[2][1] += a.z * bv.y; acc[2][2] += a.z * bv.z; acc[2][3] += a.z * bv.w;
      acc[3][0] += a.w * bv.x; acc[3][1] += a.w * bv.y; acc[3][2] += a.w * bv.z; acc[3][3] += a.w * bv.w;
    }
  }

#pragma unroll
  for (int i = 0; i < 4; ++i) {
    int r = rowBase + tr * 4 + i;
#pragma unroll
    for (int j = 0; j < 4; ++j) {
      int o = colBase + tc * 4 + j;
      out[(size_t)r * EE + o] = acc[i][j];
    }
  }
}

extern "C" void kernel_launch(void* const* d_in, const int* in_sizes, int n_in,
                              void* d_out, int out_size, void* d_ws, size_t ws_size,
                              hipStream_t stream) {
  const float* x   = (const float*)d_in[0];
  const float* Wq  = (const float*)d_in[1];
  const float* Wk  = (const float*)d_in[2];
  const float* Wv  = (const float*)d_in[3];
  const float* Wo  = (const float*)d_in[4];
  const float* rot = (const float*)d_in[5];
  float* ws  = (float*)d_ws;
  float* WqR = ws + OFF_WQR;
  float* WkR = ws + OFF_WKR;
  float* Q   = ws + OFF_Q;
  float* KV  = ws + OFF_KV;
  float* AO  = ws + OFF_AO;
  float* out = (float*)d_out;

  fold_rot_k<<<dim3((2 * EE * EE + 255) / 256), 256, 0, stream>>>(Wq, Wk, rot, WqR, WkR);
  gemm_qkv_k<<<dim3(9, 64), 256, 0, stream>>>(x, WqR, WkR, Wv, Q, KV);
  attn_k<<<dim3(BH * 2), 256, 0, stream>>>(Q, KV, AO);
  gemm_out_k<<<dim3(3, 64), 256, 0, stream>>>(AO, Wo, out);
}

// Round 5
// 99.230 us; speedup vs baseline: 2.4094x; 1.2199x over previous
//
#include <hip/hip_runtime.h>
#include <hip/hip_bf16.h>

// Problem dims
#define BB 4
#define SS 1024
#define EE 192
#define HH 64
// D = 3 (head dim)

constexpr int BH = BB * HH;  // 256

typedef float f32x2 __attribute__((ext_vector_type(2)));

// ws layout (in floats)
constexpr size_t OFF_WQR = 0;                         // E*E rotated+scaled Wq
constexpr size_t OFF_WKR = OFF_WQR + (size_t)EE*EE;   // E*E rotated Wk
constexpr size_t OFF_Q   = OFF_WKR + (size_t)EE*EE;   // (B*H, S, 4) padded
constexpr size_t SZ_Q    = (size_t)BH*SS*4;
constexpr size_t OFF_KV  = OFF_Q + SZ_Q;              // (B*H, S/2, 12): key-pair packed
constexpr size_t SZ_KV   = (size_t)BH*SS*6;
constexpr size_t OFF_AO  = OFF_KV + SZ_KV;            // (B, S, E) attention output

static __device__ __forceinline__ float fast_exp2(float x) {
#if __has_builtin(__builtin_amdgcn_exp2f)
  return __builtin_amdgcn_exp2f(x);
#else
  return exp2f(x);
#endif
}
static __device__ __forceinline__ float fast_rcp(float x) {
#if __has_builtin(__builtin_amdgcn_rcpf)
  return __builtin_amdgcn_rcpf(x);
#else
  return 1.0f / x;
#endif
}
static __device__ __forceinline__ f32x2 pk_fma(f32x2 a, f32x2 b, f32x2 c) {
#if __has_builtin(__builtin_elementwise_fma)
  return __builtin_elementwise_fma(a, b, c);
#else
  f32x2 r; r.x = fmaf(a.x, b.x, c.x); r.y = fmaf(a.y, b.y, c.y); return r;
#endif
}

// Fold per-head 3x3 rotation into Wq and Wk (fp32, exact restructuring).
// WqR additionally carries log2(e)/sqrt(3) so attention exp is a single v_exp_f32.
__global__ __launch_bounds__(256) void fold_rot_k(
    const float* __restrict__ Wq, const float* __restrict__ Wk,
    const float* __restrict__ rot, float* __restrict__ WqR, float* __restrict__ WkR)
{
  int t = blockIdx.x * 256 + threadIdx.x;
  if (t >= 2 * EE * EE) return;
  int mat = t / (EE * EE);
  int idx = t % (EE * EE);
  int op = idx / EE, e = idx % EE;      // op = h*3 + e'
  int h = op / 3, ep = op - h * 3;
  const float* W = mat ? Wk : Wq;
  float acc = 0.f;
#pragma unroll
  for (int d = 0; d < 3; ++d)
    acc += rot[h * 9 + d * 3 + ep] * W[(h * 3 + d) * EE + e];
  float scale = mat ? 1.0f : 0.8329876360019913f;  // log2(e)/sqrt(3)
  (mat ? WkR : WqR)[op * EE + e] = acc * scale;
}

// QKV projection GEMM: (4096 x 192) @ W^T for W in {WqR, WkR, Wv}.
// K/V outputs go to pair-packed layout: per key-pair (s>>1):
//   [k0_0,k0_1, k1_0,k1_1, k2_0,k2_1, v0_0,v0_1, v1_0,v1_1, v2_0,v2_1] (12 floats)
__global__ __launch_bounds__(256) void gemm_qkv_k(
    const float* __restrict__ x, const float* __restrict__ WqR,
    const float* __restrict__ WkR, const float* __restrict__ Wv,
    float* __restrict__ Q, float* __restrict__ KV)
{
  __shared__ __align__(16) float xs[64][68];
  __shared__ __align__(16) float wsm[64][68];
  int bx = blockIdx.x;   // 0..8
  int by = blockIdx.y;   // 0..63
  int t = threadIdx.x;
  int sel = bx / 3;
  const float* W = (sel == 0) ? WqR : (sel == 1 ? WkR : Wv);
  int colBase = (bx % 3) * 64;
  int rowBase = by * 64;
  int lrow = t >> 2, lq = t & 3;
  int tr = t & 15, tc = t >> 4;
  float acc[4][4] = {};

  for (int kk = 0; kk < 3; ++kk) {
    const float* xg = x + (size_t)(rowBase + lrow) * EE + kk * 64;
    const float* wg = W + (size_t)(colBase + lrow) * EE + kk * 64;
    float4 xv[4], wv[4];
#pragma unroll
    for (int i = 0; i < 4; ++i) {
      xv[i] = ((const float4*)xg)[lq + 4 * i];
      wv[i] = ((const float4*)wg)[lq + 4 * i];
    }
    __syncthreads();
#pragma unroll
    for (int i = 0; i < 4; ++i) {
      int k0 = (lq + 4 * i) * 4;
      xs[k0 + 0][lrow] = xv[i].x; xs[k0 + 1][lrow] = xv[i].y;
      xs[k0 + 2][lrow] = xv[i].z; xs[k0 + 3][lrow] = xv[i].w;
      wsm[k0 + 0][lrow] = wv[i].x; wsm[k0 + 1][lrow] = wv[i].y;
      wsm[k0 + 2][lrow] = wv[i].z; wsm[k0 + 3][lrow] = wv[i].w;
    }
    __syncthreads();
#pragma unroll 8
    for (int k = 0; k < 64; ++k) {
      float4 a = *(const float4*)&xs[k][tr * 4];
      float4 bv = *(const float4*)&wsm[k][tc * 4];
      acc[0][0] += a.x * bv.x; acc[0][1] += a.x * bv.y; acc[0][2] += a.x * bv.z; acc[0][3] += a.x * bv.w;
      acc[1][0] += a.y * bv.x; acc[1][1] += a.y * bv.y; acc[1][2] += a.y * bv.z; acc[1][3] += a.y * bv.w;
      acc[2][0] += a.z * bv.x; acc[2][1] += a.z * bv.y; acc[2][2] += a.z * bv.z; acc[2][3] += a.z * bv.w;
      acc[3][0] += a.w * bv.x; acc[3][1] += a.w * bv.y; acc[3][2] += a.w * bv.z; acc[3][3] += a.w * bv.w;
    }
  }

#pragma unroll
  for (int i = 0; i < 4; ++i) {
    int r = rowBase + tr * 4 + i;
    int b = r >> 10, s = r & (SS - 1);
#pragma unroll
    for (int j = 0; j < 4; ++j) {
      int o = colBase + tc * 4 + j;
      int h = o / 3, d = o - h * 3;
      if (sel == 0) {
        size_t base4 = ((size_t)(b * HH + h) * SS + s);
        Q[base4 * 4 + d] = acc[i][j];
      } else {
        size_t headbase = (size_t)(b * HH + h) * (SS * 6);
        int pair = s >> 1, par = s & 1;
        size_t off = headbase + (size_t)pair * 12 + (sel == 2 ? 6 : 0) + d * 2 + par;
        KV[off] = acc[i][j];
      }
    }
  }
}

// Attention: block = (head, row-quarter) -> 1024 blocks, 40KB LDS -> 4
// blocks/CU = 16 waves/CU. Within a block: 4 waves each take a 128-key-pair
// chunk, 256 rows at R=4 rows/thread. Packed fp32 math (v_pk_fma_f32):
// 7 pk-VALU + 2 exp per 2 keys. Per-wave partials reduced via LDS (exp2
// without max pass -> partials trivially additive).
__global__ __launch_bounds__(256, 4) void attn_k(
    const float* __restrict__ Qw, const float* __restrict__ KVw, float* __restrict__ AO)
{
  __shared__ __align__(16) float kvs[(SS / 2) * 12];   // 24 KB
  __shared__ __align__(16) float4 part[4][256];        // 16 KB
  int bh = blockIdx.x & 255;       // quarter-major: same-head blocks 256 apart
  int quarter = blockIdx.x >> 8;
  int b = bh >> 6, h = bh & 63;

  const float4* kvg = (const float4*)(KVw + (size_t)bh * (SS * 6));
  float4* kvs4 = (float4*)kvs;
  for (int i = threadIdx.x; i < (SS * 6) / 4; i += 256) kvs4[i] = kvg[i];
  __syncthreads();

  int lane = threadIdx.x & 63, w = threadIdx.x >> 6;
  const float* qg = Qw + (size_t)bh * (SS * 4);
  int r0 = quarter * 256 + lane;

  f32x2 q0s[4], q1s[4], q2s[4];
  f32x2 l2[4] = {}, o0[4] = {}, o1[4] = {}, o2[4] = {};
#pragma unroll
  for (int i = 0; i < 4; ++i) {
    float4 qa = *(const float4*)&qg[(size_t)(r0 + i * 64) * 4];
    q0s[i].x = qa.x; q0s[i].y = qa.x;
    q1s[i].x = qa.y; q1s[i].y = qa.y;
    q2s[i].x = qa.z; q2s[i].y = qa.z;
  }

  const float* kp = kvs + (size_t)w * 128 * 12;  // this wave's 128 key-pairs
#pragma unroll 2
  for (int p = 0; p < 128; ++p) {
    float4 A  = *(const float4*)(kp + p * 12);       // k0.xy k1.xy
    float4 Bv = *(const float4*)(kp + p * 12 + 4);   // k2.xy v0.xy
    float4 C  = *(const float4*)(kp + p * 12 + 8);   // v1.xy v2.xy
    f32x2 k0; k0.x = A.x;  k0.y = A.y;
    f32x2 k1; k1.x = A.z;  k1.y = A.w;
    f32x2 k2; k2.x = Bv.x; k2.y = Bv.y;
    f32x2 v0; v0.x = Bv.z; v0.y = Bv.w;
    f32x2 v1; v1.x = C.x;  v1.y = C.y;
    f32x2 v2; v2.x = C.z;  v2.y = C.w;
#pragma unroll
    for (int i = 0; i < 4; ++i) {
      f32x2 s2 = pk_fma(q0s[i], k0, pk_fma(q1s[i], k1, q2s[i] * k2));
      f32x2 P;
      P.x = fast_exp2(s2.x);   // exp(qk/sqrt(3)); log2e/sqrt3 folded into Q
      P.y = fast_exp2(s2.y);
      l2[i] += P;
      o0[i] = pk_fma(P, v0, o0[i]);
      o1[i] = pk_fma(P, v1, o1[i]);
      o2[i] = pk_fma(P, v2, o2[i]);
    }
  }

#pragma unroll
  for (int i = 0; i < 4; ++i)
    part[w][i * 64 + lane] = make_float4(l2[i].x + l2[i].y, o0[i].x + o0[i].y,
                                         o1[i].x + o1[i].y, o2[i].x + o2[i].y);
  __syncthreads();

  int row = threadIdx.x;
  float4 p0 = part[0][row], p1 = part[1][row], p2 = part[2][row], p3 = part[3][row];
  float lt = (p0.x + p1.x) + (p2.x + p3.x);
  float a0 = (p0.y + p1.y) + (p2.y + p3.y);
  float a1 = (p0.z + p1.z) + (p2.z + p3.z);
  float a2 = (p0.w + p1.w) + (p2.w + p3.w);
  float inv = fast_rcp(lt);
  int r = quarter * 256 + row;
  float* dst = AO + ((size_t)(b * SS + r)) * EE + h * 3;
  dst[0] = a0 * inv; dst[1] = a1 * inv; dst[2] = a2 * inv;
}

// Output projection: AO (4096 x 192) @ Wo^T -> out. grid = (3, 64).
__global__ __launch_bounds__(256) void gemm_out_k(
    const float* __restrict__ x, const float* __restrict__ Wo, float* __restrict__ out)
{
  __shared__ __align__(16) float xs[64][68];
  __shared__ __align__(16) float wsm[64][68];
  int bx = blockIdx.x;   // 0..2
  int by = blockIdx.y;   // 0..63
  int t = threadIdx.x;
  int colBase = bx * 64;
  int rowBase = by * 64;
  int lrow = t >> 2, lq = t & 3;
  int tr = t & 15, tc = t >> 4;
  float acc[4][4] = {};

  for (int kk = 0; kk < 3; ++kk) {
    const float* xg = x + (size_t)(rowBase + lrow) * EE + kk * 64;
    const float* wg = Wo + (size_t)(colBase + lrow) * EE + kk * 64;
    float4 xv[4], wv[4];
#pragma unroll
    for (int i = 0; i < 4; ++i) {
      xv[i] = ((const float4*)xg)[lq + 4 * i];
      wv[i] = ((const float4*)wg)[lq + 4 * i];
    }
    __syncthreads();
#pragma unroll
    for (int i = 0; i < 4; ++i) {
      int k0 = (lq + 4 * i) * 4;
      xs[k0 + 0][lrow] = xv[i].x; xs[k0 + 1][lrow] = xv[i].y;
      xs[k0 + 2][lrow] = xv[i].z; xs[k0 + 3][lrow] = xv[i].w;
      wsm[k0 + 0][lrow] = wv[i].x; wsm[k0 + 1][lrow] = wv[i].y;
      wsm[k0 + 2][lrow] = wv[i].z; wsm[k0 + 3][lrow] = wv[i].w;
    }
    __syncthreads();
#pragma unroll 8
    for (int k = 0; k < 64; ++k) {
      float4 a = *(const float4*)&xs[k][tr * 4];
      float4 bv = *(const float4*)&wsm[k][tc * 4];
      acc[0][0] += a.x * bv.x; acc[0][1] += a.x * bv.y; acc[0][2] += a.x * bv.z; acc[0][3] += a.x * bv.w;
      acc[1][0] += a.y * bv.x; acc[1][1] += a.y * bv.y; acc[1][2] += a.y * bv.z; acc[1][3] += a.y * bv.w;
      acc[2][0] += a.z * bv.x; acc[2][1] += a.z * bv.y; acc[2][2] += a.z * bv.z; acc[2][3] += a.z * bv.w;
      acc[3][0] += a.w * bv.x; acc[3][1] += a.w * bv.y; acc[3][2] += a.w * bv.z; acc[3][3] += a.w * bv.w;
    }
  }

#pragma unroll
  for (int i = 0; i < 4; ++i) {
    int r = rowBase + tr * 4 + i;
#pragma unroll
    for (int j = 0; j < 4; ++j) {
      int o = colBase + tc * 4 + j;
      out[(size_t)r * EE + o] = acc[i][j];
    }
  }
}

extern "C" void kernel_launch(void* const* d_in, const int* in_sizes, int n_in,
                              void* d_out, int out_size, void* d_ws, size_t ws_size,
                              hipStream_t stream) {
  const float* x   = (const float*)d_in[0];
  const float* Wq  = (const float*)d_in[1];
  const float* Wk  = (const float*)d_in[2];
  const float* Wv  = (const float*)d_in[3];
  const float* Wo  = (const float*)d_in[4];
  const float* rot = (const float*)d_in[5];
  float* ws  = (float*)d_ws;
  float* WqR = ws + OFF_WQR;
  float* WkR = ws + OFF_WKR;
  float* Q   = ws + OFF_Q;
  float* KV  = ws + OFF_KV;
  float* AO  = ws + OFF_AO;
  float* out = (float*)d_out;

  fold_rot_k<<<dim3((2 * EE * EE + 255) / 256), 256, 0, stream>>>(Wq, Wk, rot, WqR, WkR);
  gemm_qkv_k<<<dim3(9, 64), 256, 0, stream>>>(x, WqR, WkR, Wv, Q, KV);
  attn_k<<<dim3(BH * 4), 256, 0, stream>>>(Q, KV, AO);
  gemm_out_k<<<dim3(3, 64), 256, 0, stream>>>(AO, Wo, out);
}

// Round 6
// 82.851 us; speedup vs baseline: 2.8857x; 1.1977x over previous
//
#include <hip/hip_runtime.h>
#include <hip/hip_bf16.h>

// Problem dims
#define BB 4
#define SS 1024
#define EE 192
#define HH 64
// D = 3 (head dim)

constexpr int BH = BB * HH;  // 256

typedef __attribute__((ext_vector_type(8))) short bs8;    // 8 bf16 = 4 VGPR (MFMA A/B frag)
typedef __attribute__((ext_vector_type(16))) float fx16;  // MFMA C/D frag
union U4B { uint4 u; bs8 s; };

// ws layout (in floats)
constexpr size_t OFF_WQR = 0;                          // E*E rotated+scaled Wq
constexpr size_t OFF_WKR = OFF_WQR + (size_t)EE*EE;    // E*E rotated Wk
constexpr size_t OFF_Q   = OFF_WKR + (size_t)EE*EE;    // (B*H, S, 4) fp32
constexpr size_t OFF_KF  = OFF_Q  + (size_t)BH*SS*4;   // (B*H, S, 8) bf16: k0 k1 k2 0*5
constexpr size_t OFF_VC  = OFF_KF + (size_t)BH*SS*4;   // (B*H, 4, S) bf16 col-major: v0 v1 v2 ones
constexpr size_t OFF_AO  = OFF_VC + (size_t)BH*SS*2;   // (B, S, E) fp32

static __device__ __forceinline__ float fast_exp2(float x) {
#if __has_builtin(__builtin_amdgcn_exp2f)
  return __builtin_amdgcn_exp2f(x);
#else
  return exp2f(x);
#endif
}
static __device__ __forceinline__ float fast_rcp(float x) {
#if __has_builtin(__builtin_amdgcn_rcpf)
  return __builtin_amdgcn_rcpf(x);
#else
  return 1.0f / x;
#endif
}

// Prefill: Kf all zeros (gemm then writes slots 0-2); Vc row 3 = bf16(1.0)
// (ones column makes PV MFMA also produce the exp-sum l for free).
__global__ __launch_bounds__(256) void init_k(uint4* __restrict__ Kf, uint4* __restrict__ Vc) {
  int t = blockIdx.x * 256 + threadIdx.x;
  if (t < BH * SS) {                       // 262144 uint4 = 4MB zeros
    Kf[t] = make_uint4(0u, 0u, 0u, 0u);
  } else {
    int u = t - BH * SS;
    if (u < BH * SS / 8) {                 // 32768 uint4 of bf16(1.0) pairs
      int bh = u >> 7, i = u & 127;
      unsigned v = 0x3F803F80u;
      Vc[(size_t)bh * 512 + 384 + i] = make_uint4(v, v, v, v);
    }
  }
}

// Fold per-head 3x3 rotation into Wq and Wk (fp32, exact restructuring).
// WqR additionally carries log2(e)/sqrt(3) so attention exp is a single v_exp_f32.
__global__ __launch_bounds__(256) void fold_rot_k(
    const float* __restrict__ Wq, const float* __restrict__ Wk,
    const float* __restrict__ rot, float* __restrict__ WqR, float* __restrict__ WkR)
{
  int t = blockIdx.x * 256 + threadIdx.x;
  if (t >= 2 * EE * EE) return;
  int mat = t / (EE * EE);
  int idx = t % (EE * EE);
  int op = idx / EE, e = idx % EE;      // op = h*3 + e'
  int h = op / 3, ep = op - h * 3;
  const float* W = mat ? Wk : Wq;
  float acc = 0.f;
#pragma unroll
  for (int d = 0; d < 3; ++d)
    acc += rot[h * 9 + d * 3 + ep] * W[(h * 3 + d) * EE + e];
  float scale = mat ? 1.0f : 0.8329876360019913f;  // log2(e)/sqrt(3)
  (mat ? WkR : WqR)[op * EE + e] = acc * scale;
}

// QKV projection GEMM: (4096 x 192) @ W^T for W in {WqR, WkR, Wv}.
// Q -> fp32 (B*H,S,4); K -> bf16 (B*H,S,8) slots 0-2; V -> bf16 col-major (B*H,4,S).
__global__ __launch_bounds__(256) void gemm_qkv_k(
    const float* __restrict__ x, const float* __restrict__ WqR,
    const float* __restrict__ WkR, const float* __restrict__ Wv,
    float* __restrict__ Q, __hip_bfloat16* __restrict__ Kf, __hip_bfloat16* __restrict__ Vc)
{
  __shared__ __align__(16) float xs[64][68];
  __shared__ __align__(16) float wsm[64][68];
  int bx = blockIdx.x;   // 0..8
  int by = blockIdx.y;   // 0..63
  int t = threadIdx.x;
  int sel = bx / 3;
  const float* W = (sel == 0) ? WqR : (sel == 1 ? WkR : Wv);
  int colBase = (bx % 3) * 64;
  int rowBase = by * 64;
  int lrow = t >> 2, lq = t & 3;
  int tr = t & 15, tc = t >> 4;
  float acc[4][4] = {};

  for (int kk = 0; kk < 3; ++kk) {
    const float* xg = x + (size_t)(rowBase + lrow) * EE + kk * 64;
    const float* wg = W + (size_t)(colBase + lrow) * EE + kk * 64;
    float4 xv[4], wv[4];
#pragma unroll
    for (int i = 0; i < 4; ++i) {
      xv[i] = ((const float4*)xg)[lq + 4 * i];
      wv[i] = ((const float4*)wg)[lq + 4 * i];
    }
    __syncthreads();
#pragma unroll
    for (int i = 0; i < 4; ++i) {
      int k0 = (lq + 4 * i) * 4;
      xs[k0 + 0][lrow] = xv[i].x; xs[k0 + 1][lrow] = xv[i].y;
      xs[k0 + 2][lrow] = xv[i].z; xs[k0 + 3][lrow] = xv[i].w;
      wsm[k0 + 0][lrow] = wv[i].x; wsm[k0 + 1][lrow] = wv[i].y;
      wsm[k0 + 2][lrow] = wv[i].z; wsm[k0 + 3][lrow] = wv[i].w;
    }
    __syncthreads();
#pragma unroll 8
    for (int k = 0; k < 64; ++k) {
      float4 a = *(const float4*)&xs[k][tr * 4];
      float4 bv = *(const float4*)&wsm[k][tc * 4];
      acc[0][0] += a.x * bv.x; acc[0][1] += a.x * bv.y; acc[0][2] += a.x * bv.z; acc[0][3] += a.x * bv.w;
      acc[1][0] += a.y * bv.x; acc[1][1] += a.y * bv.y; acc[1][2] += a.y * bv.z; acc[1][3] += a.y * bv.w;
      acc[2][0] += a.z * bv.x; acc[2][1] += a.z * bv.y; acc[2][2] += a.z * bv.z; acc[2][3] += a.z * bv.w;
      acc[3][0] += a.w * bv.x; acc[3][1] += a.w * bv.y; acc[3][2] += a.w * bv.z; acc[3][3] += a.w * bv.w;
    }
  }

#pragma unroll
  for (int i = 0; i < 4; ++i) {
    int r = rowBase + tr * 4 + i;
    int b = r >> 10, s = r & (SS - 1);
#pragma unroll
    for (int j = 0; j < 4; ++j) {
      int o = colBase + tc * 4 + j;
      int h = o / 3, d = o - h * 3;
      size_t bh = (size_t)(b * HH + h);
      if (sel == 0)      Q[(bh * SS + s) * 4 + d] = acc[i][j];
      else if (sel == 1) Kf[(bh * SS + s) * 8 + d] = __float2bfloat16(acc[i][j]);
      else               Vc[bh * (4 * SS) + (size_t)d * SS + s] = __float2bfloat16(acc[i][j]);
    }
  }
}

// MFMA attention. Block = (head, query-quarter): 1024 blocks, 4 waves, each
// wave owns 2 query-blocks of 32 and sweeps all 32 key-tiles.
// Swapped QK^T (A=K, B=Q) -> D[key][query]: each lane's 16 scores belong to
// its own query (col=lane&31). exp2 in-register, cvt_pk_bf16 + 2x
// permlane32_swap builds the PV A-frags in-register (T12), V ones-column
// yields l via the same PV MFMA. No max pass (scores bounded, fp32/bf16 range ample).
__global__ __launch_bounds__(256, 4) void attn_k(
    const float* __restrict__ Qw, const unsigned short* __restrict__ Kfg,
    const unsigned short* __restrict__ Vcg, float* __restrict__ AO)
{
  __shared__ __align__(16) short KfL[1025 * 8];   // 16.02 KB, row 1024 = zeros (h1 lanes)
  __shared__ __align__(16) short VcL[4 * 1040];   // 8.1 KB, pad 16 -> conflict-free
  int bh = blockIdx.x & 255;       // quarter-major: same-head blocks 256 apart (same XCD)
  int quarter = blockIdx.x >> 8;
  int b = bh >> 6, h = bh & 63;

  // stage K (XOR-swizzled so A-frag reads are bank-conflict-free) and V
  const uint4* ksrc = (const uint4*)Kfg + (size_t)bh * 1024;
  uint4* kdst = (uint4*)KfL;
  for (int i = threadIdx.x; i < 1024; i += 256) kdst[i ^ ((i >> 3) & 7)] = ksrc[i];
  if (threadIdx.x == 0) kdst[1024] = make_uint4(0u, 0u, 0u, 0u);
  const uint4* vsrc = (const uint4*)Vcg + (size_t)bh * 512;
  for (int i = threadIdx.x; i < 512; i += 256) {
    int r = i >> 7, cq = i & 127;
    *(uint4*)(VcL + r * 1040 + cq * 8) = vsrc[i];
  }
  __syncthreads();

  int lane = threadIdx.x & 63, w = threadIdx.x >> 6;
  int h32 = lane >> 5;          // lane half
  int col = lane & 31;          // query (B/D col) / key (A row)
  int qbase = quarter * 256 + w * 64;

  // Q B-frags for the wave's 2 query blocks (h1 lanes = zero half of K-dim)
  U4B bq[2];
#pragma unroll
  for (int qb = 0; qb < 2; ++qb) {
    int qrow = qbase + qb * 32 + col;
    float4 qv = *(const float4*)&Qw[((size_t)bh * SS + qrow) * 4];
    unsigned pa, pb;
    asm("v_cvt_pk_bf16_f32 %0, %1, %2" : "=v"(pa) : "v"(qv.x), "v"(qv.y));
    asm("v_cvt_pk_bf16_f32 %0, %1, %2" : "=v"(pb) : "v"(qv.z), "v"(0.0f));
    bq[qb].u = make_uint4(h32 ? 0u : pa, h32 ? 0u : pb, 0u, 0u);
  }

  const fx16 zc = {0,0,0,0, 0,0,0,0, 0,0,0,0, 0,0,0,0};
  fx16 accPV[2] = {zc, zc};
  int vbase = (col & 3) * 1040 + 8 * h32;

  for (int kt = 0; kt < 32; ++kt) {
    // K A-frag: lane = key kt*32+col (h0 half holds d=0..2, h1 half zeros)
    int key = kt * 32 + col;
    int koff = h32 ? 8192 : ((key * 8) ^ (((key >> 3) & 7) << 3));
    U4B ak; ak.u = *(const uint4*)(KfL + koff);
    // V B-frags (keys kt*32+0..15 and +16..31), col&3 selects v0/v1/v2/ones
    U4B bv1; bv1.u = *(const uint4*)(VcL + vbase + kt * 32);
    U4B bv2; bv2.u = *(const uint4*)(VcL + vbase + kt * 32 + 16);

#pragma unroll
    for (int qb = 0; qb < 2; ++qb) {
      fx16 S = __builtin_amdgcn_mfma_f32_32x32x16_bf16(ak.s, bq[qb].s, zc, 0, 0, 0);
#pragma unroll
      for (int i = 0; i < 16; ++i) S[i] = fast_exp2(S[i]);  // P (log2e/sqrt3 in Q)
      unsigned u0, u1, u2, u3, u4, u5, u6, u7;
      asm("v_cvt_pk_bf16_f32 %0, %1, %2" : "=v"(u0) : "v"(S[0]),  "v"(S[1]));
      asm("v_cvt_pk_bf16_f32 %0, %1, %2" : "=v"(u1) : "v"(S[2]),  "v"(S[3]));
      asm("v_cvt_pk_bf16_f32 %0, %1, %2" : "=v"(u2) : "v"(S[4]),  "v"(S[5]));
      asm("v_cvt_pk_bf16_f32 %0, %1, %2" : "=v"(u3) : "v"(S[6]),  "v"(S[7]));
      asm("v_cvt_pk_bf16_f32 %0, %1, %2" : "=v"(u4) : "v"(S[8]),  "v"(S[9]));
      asm("v_cvt_pk_bf16_f32 %0, %1, %2" : "=v"(u5) : "v"(S[10]), "v"(S[11]));
      asm("v_cvt_pk_bf16_f32 %0, %1, %2" : "=v"(u6) : "v"(S[12]), "v"(S[13]));
      asm("v_cvt_pk_bf16_f32 %0, %1, %2" : "=v"(u7) : "v"(S[14]), "v"(S[15]));
      // redistribute D-layout (key groups of 4) -> A-frag (key groups of 8)
      asm("v_permlane32_swap_b32 %0, %1" : "+v"(u0), "+v"(u2));
      asm("v_permlane32_swap_b32 %0, %1" : "+v"(u1), "+v"(u3));
      asm("v_permlane32_swap_b32 %0, %1" : "+v"(u4), "+v"(u6));
      asm("v_permlane32_swap_b32 %0, %1" : "+v"(u5), "+v"(u7));
      U4B p1; p1.u = make_uint4(u0, u1, u2, u3);  // keys kt*32+0..15
      U4B p2; p2.u = make_uint4(u4, u5, u6, u7);  // keys kt*32+16..31
      accPV[qb] = __builtin_amdgcn_mfma_f32_32x32x16_bf16(p1.s, bv1.s, accPV[qb], 0, 0, 0);
      accPV[qb] = __builtin_amdgcn_mfma_f32_32x32x16_bf16(p2.s, bv2.s, accPV[qb], 0, 0, 0);
    }
  }

  // Epilogue: D_pv[query row][col]: col 0-2 = o, col 3 = l. Normalize + write.
  int base3 = (lane & 32) | 3;
#pragma unroll
  for (int qb = 0; qb < 2; ++qb) {
    float inv[16];
#pragma unroll
    for (int rg = 0; rg < 16; ++rg)
      inv[rg] = __shfl(fast_rcp(accPV[qb][rg]), base3, 64);
    if (col < 3) {
      int q32 = qbase + qb * 32;
#pragma unroll
      for (int rg = 0; rg < 16; ++rg) {
        int row = (rg & 3) + 8 * (rg >> 2) + 4 * h32;
        AO[((size_t)(b * SS + q32 + row)) * EE + h * 3 + col] = accPV[qb][rg] * inv[rg];
      }
    }
  }
}

// Output projection: AO (4096 x 192) @ Wo^T -> out. grid = (3, 64).
__global__ __launch_bounds__(256) void gemm_out_k(
    const float* __restrict__ x, const float* __restrict__ Wo, float* __restrict__ out)
{
  __shared__ __align__(16) float xs[64][68];
  __shared__ __align__(16) float wsm[64][68];
  int bx = blockIdx.x;   // 0..2
  int by = blockIdx.y;   // 0..63
  int t = threadIdx.x;
  int colBase = bx * 64;
  int rowBase = by * 64;
  int lrow = t >> 2, lq = t & 3;
  int tr = t & 15, tc = t >> 4;
  float acc[4][4] = {};

  for (int kk = 0; kk < 3; ++kk) {
    const float* xg = x + (size_t)(rowBase + lrow) * EE + kk * 64;
    const float* wg = Wo + (size_t)(colBase + lrow) * EE + kk * 64;
    float4 xv[4], wv[4];
#pragma unroll
    for (int i = 0; i < 4; ++i) {
      xv[i] = ((const float4*)xg)[lq + 4 * i];
      wv[i] = ((const float4*)wg)[lq + 4 * i];
    }
    __syncthreads();
#pragma unroll
    for (int i = 0; i < 4; ++i) {
      int k0 = (lq + 4 * i) * 4;
      xs[k0 + 0][lrow] = xv[i].x; xs[k0 + 1][lrow] = xv[i].y;
      xs[k0 + 2][lrow] = xv[i].z; xs[k0 + 3][lrow] = xv[i].w;
      wsm[k0 + 0][lrow] = wv[i].x; wsm[k0 + 1][lrow] = wv[i].y;
      wsm[k0 + 2][lrow] = wv[i].z; wsm[k0 + 3][lrow] = wv[i].w;
    }
    __syncthreads();
#pragma unroll 8
    for (int k = 0; k < 64; ++k) {
      float4 a = *(const float4*)&xs[k][tr * 4];
      float4 bv = *(const float4*)&wsm[k][tc * 4];
      acc[0][0] += a.x * bv.x; acc[0][1] += a.x * bv.y; acc[0][2] += a.x * bv.z; acc[0][3] += a.x * bv.w;
      acc[1][0] += a.y * bv.x; acc[1][1] += a.y * bv.y; acc[1][2] += a.y * bv.z; acc[1][3] += a.y * bv.w;
      acc[2][0] += a.z * bv.x; acc[2][1] += a.z * bv.y; acc[2][2] += a.z * bv.z; acc[2][3] += a.z * bv.w;
      acc[3][0] += a.w * bv.x; acc[3][1] += a.w * bv.y; acc[3][2] += a.w * bv.z; acc[3][3] += a.w * bv.w;
    }
  }

#pragma unroll
  for (int i = 0; i < 4; ++i) {
    int r = rowBase + tr * 4 + i;
#pragma unroll
    for (int j = 0; j < 4; ++j) {
      int o = colBase + tc * 4 + j;
      out[(size_t)r * EE + o] = acc[i][j];
    }
  }
}

extern "C" void kernel_launch(void* const* d_in, const int* in_sizes, int n_in,
                              void* d_out, int out_size, void* d_ws, size_t ws_size,
                              hipStream_t stream) {
  const float* x   = (const float*)d_in[0];
  const float* Wq  = (const float*)d_in[1];
  const float* Wk  = (const float*)d_in[2];
  const float* Wv  = (const float*)d_in[3];
  const float* Wo  = (const float*)d_in[4];
  const float* rot = (const float*)d_in[5];
  float* ws  = (float*)d_ws;
  float* WqR = ws + OFF_WQR;
  float* WkR = ws + OFF_WKR;
  float* Q   = ws + OFF_Q;
  unsigned short* Kf = (unsigned short*)(ws + OFF_KF);
  unsigned short* Vc = (unsigned short*)(ws + OFF_VC);
  float* AO  = ws + OFF_AO;
  float* out = (float*)d_out;

  init_k<<<dim3((BH * SS + BH * SS / 8) / 256), 256, 0, stream>>>((uint4*)Kf, (uint4*)Vc);
  fold_rot_k<<<dim3((2 * EE * EE + 255) / 256), 256, 0, stream>>>(Wq, Wk, rot, WqR, WkR);
  gemm_qkv_k<<<dim3(9, 64), 256, 0, stream>>>(x, WqR, WkR, Wv, Q,
                                              (__hip_bfloat16*)Kf, (__hip_bfloat16*)Vc);
  attn_k<<<dim3(BH * 4), 256, 0, stream>>>(Q, Kf, Vc, AO);
  gemm_out_k<<<dim3(3, 64), 256, 0, stream>>>(AO, Wo, out);
}

// Round 7
// 77.497 us; speedup vs baseline: 3.0851x; 1.0691x over previous
//
#include <hip/hip_runtime.h>
#include <hip/hip_bf16.h>

// Problem dims
#define BB 4
#define SS 1024
#define EE 192
#define HH 64
// D = 3 (head dim)

constexpr int BH = BB * HH;  // 256

typedef __attribute__((ext_vector_type(8))) short bs8;    // 8 bf16 = 4 VGPR (MFMA A/B frag)
typedef __attribute__((ext_vector_type(16))) float fx16;  // MFMA C/D frag
union U4B { uint4 u; bs8 s; };

// ws layout (in floats)
constexpr size_t OFF_WQR = 0;                          // E*E rotated+scaled Wq
constexpr size_t OFF_WKR = OFF_WQR + (size_t)EE*EE;    // E*E rotated Wk
constexpr size_t OFF_Q   = OFF_WKR + (size_t)EE*EE;    // (B*H, S, 4) fp32
constexpr size_t OFF_KF  = OFF_Q  + (size_t)BH*SS*4;   // (B*H, S, 4) bf16: k0 k1 k2 0
constexpr size_t OFF_VC  = OFF_KF + (size_t)BH*SS*2;   // (B*H, 3, S) bf16 col-major
constexpr size_t OFF_AO  = OFF_VC + (size_t)BH*SS*3/2; // (B, S, E) fp32

static __device__ __forceinline__ float fast_exp2(float x) {
#if __has_builtin(__builtin_amdgcn_exp2f)
  return __builtin_amdgcn_exp2f(x);
#else
  return exp2f(x);
#endif
}
static __device__ __forceinline__ float fast_rcp(float x) {
#if __has_builtin(__builtin_amdgcn_rcpf)
  return __builtin_amdgcn_rcpf(x);
#else
  return 1.0f / x;
#endif
}

// Fold per-head 3x3 rotation into Wq and Wk (fp32, exact restructuring).
// WqR additionally carries log2(e)/sqrt(3) so attention exp is a single v_exp_f32.
__global__ __launch_bounds__(256) void fold_rot_k(
    const float* __restrict__ Wq, const float* __restrict__ Wk,
    const float* __restrict__ rot, float* __restrict__ WqR, float* __restrict__ WkR)
{
  int t = blockIdx.x * 256 + threadIdx.x;
  if (t >= 2 * EE * EE) return;
  int mat = t / (EE * EE);
  int idx = t % (EE * EE);
  int op = idx / EE, e = idx % EE;      // op = h*3 + e'
  int h = op / 3, ep = op - h * 3;
  const float* W = mat ? Wk : Wq;
  float acc = 0.f;
#pragma unroll
  for (int d = 0; d < 3; ++d)
    acc += rot[h * 9 + d * 3 + ep] * W[(h * 3 + d) * EE + e];
  float scale = mat ? 1.0f : 0.8329876360019913f;  // log2(e)/sqrt(3)
  (mat ? WkR : WqR)[op * EE + e] = acc * scale;
}

// QKV projection GEMM: (4096 x 192) @ W^T for W in {WqR, WkR, Wv}.
// Q -> fp32 (B*H,S,4); K -> bf16 (B*H,S,4) slot3=0; V -> bf16 col-major (B*H,3,S).
__global__ __launch_bounds__(256) void gemm_qkv_k(
    const float* __restrict__ x, const float* __restrict__ WqR,
    const float* __restrict__ WkR, const float* __restrict__ Wv,
    float* __restrict__ Q, __hip_bfloat16* __restrict__ Kf, __hip_bfloat16* __restrict__ Vc)
{
  __shared__ __align__(16) float xs[64][68];
  __shared__ __align__(16) float wsm[64][68];
  int bx = blockIdx.x;   // 0..8
  int by = blockIdx.y;   // 0..63
  int t = threadIdx.x;
  int sel = bx / 3;
  const float* W = (sel == 0) ? WqR : (sel == 1 ? WkR : Wv);
  int colBase = (bx % 3) * 64;
  int rowBase = by * 64;
  int lrow = t >> 2, lq = t & 3;
  int tr = t & 15, tc = t >> 4;
  float acc[4][4] = {};

  for (int kk = 0; kk < 3; ++kk) {
    const float* xg = x + (size_t)(rowBase + lrow) * EE + kk * 64;
    const float* wg = W + (size_t)(colBase + lrow) * EE + kk * 64;
    float4 xv[4], wv[4];
#pragma unroll
    for (int i = 0; i < 4; ++i) {
      xv[i] = ((const float4*)xg)[lq + 4 * i];
      wv[i] = ((const float4*)wg)[lq + 4 * i];
    }
    __syncthreads();
#pragma unroll
    for (int i = 0; i < 4; ++i) {
      int k0 = (lq + 4 * i) * 4;
      xs[k0 + 0][lrow] = xv[i].x; xs[k0 + 1][lrow] = xv[i].y;
      xs[k0 + 2][lrow] = xv[i].z; xs[k0 + 3][lrow] = xv[i].w;
      wsm[k0 + 0][lrow] = wv[i].x; wsm[k0 + 1][lrow] = wv[i].y;
      wsm[k0 + 2][lrow] = wv[i].z; wsm[k0 + 3][lrow] = wv[i].w;
    }
    __syncthreads();
#pragma unroll 8
    for (int k = 0; k < 64; ++k) {
      float4 a = *(const float4*)&xs[k][tr * 4];
      float4 bv = *(const float4*)&wsm[k][tc * 4];
      acc[0][0] += a.x * bv.x; acc[0][1] += a.x * bv.y; acc[0][2] += a.x * bv.z; acc[0][3] += a.x * bv.w;
      acc[1][0] += a.y * bv.x; acc[1][1] += a.y * bv.y; acc[1][2] += a.y * bv.z; acc[1][3] += a.y * bv.w;
      acc[2][0] += a.z * bv.x; acc[2][1] += a.z * bv.y; acc[2][2] += a.z * bv.z; acc[2][3] += a.z * bv.w;
      acc[3][0] += a.w * bv.x; acc[3][1] += a.w * bv.y; acc[3][2] += a.w * bv.z; acc[3][3] += a.w * bv.w;
    }
  }

#pragma unroll
  for (int i = 0; i < 4; ++i) {
    int r = rowBase + tr * 4 + i;
    int b = r >> 10, s = r & (SS - 1);
#pragma unroll
    for (int j = 0; j < 4; ++j) {
      int o = colBase + tc * 4 + j;
      int h = o / 3, d = o - h * 3;
      size_t bh = (size_t)(b * HH + h);
      if (sel == 0) {
        Q[(bh * SS + s) * 4 + d] = acc[i][j];
      } else if (sel == 1) {
        Kf[(bh * SS + s) * 4 + d] = __float2bfloat16(acc[i][j]);
        if (d == 2) Kf[(bh * SS + s) * 4 + 3] = __float2bfloat16(0.0f);  // finite pad for A-frag
      } else {
        Vc[bh * (3 * SS) + (size_t)d * SS + s] = __float2bfloat16(acc[i][j]);
      }
    }
  }
}

// MFMA attention. Block = (head, query-eighth): 2048 blocks, 16.3KB LDS ->
// 8 blocks/CU = 32 waves/CU. Each wave owns ONE query-block of 32, sweeps 32
// key-tiles. Swapped QK^T (A=K, B=Q) -> D[key][query]; since B(=Q) is zero
// for k>=3, A's k>=3 content is irrelevant (finite junk ok) -> K stored as
// (S,4) bf16, A-frag = {k-pair, 0, 0} in-register, no zero rows needed.
// exp2 in-register, cvt_pk + permlane32_swap -> PV A-frags (T12); V
// ones-column (written into LDS locally) yields l via the PV MFMA.
__global__ __launch_bounds__(256, 8) void attn_k(
    const float* __restrict__ Qw, const unsigned short* __restrict__ Kfg,
    const unsigned short* __restrict__ Vcg, float* __restrict__ AO)
{
  __shared__ __align__(16) short KfL[1024 * 4];   // 8 KB: [key][k0 k1 k2 0]
  __shared__ __align__(16) short VcL[4 * 1040];   // 8.1 KB: rows v0 v1 v2 ones
  int bh = blockIdx.x & 255;       // eighth-major: same-head blocks 256 apart (same XCD)
  int eighth = blockIdx.x >> 8;
  int b = bh >> 6, h = bh & 63;

  // stage K: plain uint2 copy (slot3 already zero from gemm)
  const uint2* ksrc = (const uint2*)Kfg + (size_t)bh * 1024;
  uint2* kdst = (uint2*)KfL;
  for (int i = threadIdx.x; i < 1024; i += 256) kdst[i] = ksrc[i];
  // stage V rows 0-2; row 3 = bf16(1.0) ones, generated locally
  const uint4* vsrc = (const uint4*)Vcg + (size_t)bh * 384;
  for (int i = threadIdx.x; i < 384; i += 256) {
    int r = i >> 7, cq = i & 127;
    *(uint4*)(VcL + r * 1040 + cq * 8) = vsrc[i];
  }
  {
    unsigned v1 = 0x3F803F80u;
    for (int i = threadIdx.x; i < 128; i += 256)
      *(uint4*)(VcL + 3 * 1040 + i * 8) = make_uint4(v1, v1, v1, v1);
  }
  __syncthreads();

  int lane = threadIdx.x & 63, w = threadIdx.x >> 6;
  int h32 = lane >> 5;          // lane half
  int col = lane & 31;          // query (B col) / key (A row)
  int q32 = eighth * 128 + w * 32;

  // Q B-frag (h1 lanes = zero half of K-dim; k=3..7 zero)
  float4 qv = *(const float4*)&Qw[((size_t)bh * SS + q32 + col) * 4];
  unsigned pa, pb;
  asm("v_cvt_pk_bf16_f32 %0, %1, %2" : "=v"(pa) : "v"(qv.x), "v"(qv.y));
  asm("v_cvt_pk_bf16_f32 %0, %1, %2" : "=v"(pb) : "v"(qv.z), "v"(0.0f));
  U4B bq; bq.u = make_uint4(h32 ? 0u : pa, h32 ? 0u : pb, 0u, 0u);

  const fx16 zc = {0,0,0,0, 0,0,0,0, 0,0,0,0, 0,0,0,0};
  fx16 accPV = zc;
  int vbase = (col & 3) * 1040 + 8 * h32;

  for (int kt = 0; kt < 32; ++kt) {
    // K A-frag: all lanes read key kt*32+col (h1 = broadcast copy; its k-slots
    // multiply B=0). uint2 -> regs 0-1, regs 2-3 = 0.
    uint2 kk = *(const uint2*)(KfL + (size_t)(kt * 32 + col) * 4);
    U4B ak; ak.u = make_uint4(kk.x, kk.y, 0u, 0u);
    // V B-frags (keys kt*32+0..15 and +16..31), col&3 selects v0/v1/v2/ones
    U4B bv1; bv1.u = *(const uint4*)(VcL + vbase + kt * 32);
    U4B bv2; bv2.u = *(const uint4*)(VcL + vbase + kt * 32 + 16);

    fx16 S = __builtin_amdgcn_mfma_f32_32x32x16_bf16(ak.s, bq.s, zc, 0, 0, 0);
#pragma unroll
    for (int i = 0; i < 16; ++i) S[i] = fast_exp2(S[i]);  // P (log2e/sqrt3 in Q)
    unsigned u0, u1, u2, u3, u4, u5, u6, u7;
    asm("v_cvt_pk_bf16_f32 %0, %1, %2" : "=v"(u0) : "v"(S[0]),  "v"(S[1]));
    asm("v_cvt_pk_bf16_f32 %0, %1, %2" : "=v"(u1) : "v"(S[2]),  "v"(S[3]));
    asm("v_cvt_pk_bf16_f32 %0, %1, %2" : "=v"(u2) : "v"(S[4]),  "v"(S[5]));
    asm("v_cvt_pk_bf16_f32 %0, %1, %2" : "=v"(u3) : "v"(S[6]),  "v"(S[7]));
    asm("v_cvt_pk_bf16_f32 %0, %1, %2" : "=v"(u4) : "v"(S[8]),  "v"(S[9]));
    asm("v_cvt_pk_bf16_f32 %0, %1, %2" : "=v"(u5) : "v"(S[10]), "v"(S[11]));
    asm("v_cvt_pk_bf16_f32 %0, %1, %2" : "=v"(u6) : "v"(S[12]), "v"(S[13]));
    asm("v_cvt_pk_bf16_f32 %0, %1, %2" : "=v"(u7) : "v"(S[14]), "v"(S[15]));
    // redistribute D-layout (key groups of 4) -> A-frag (key groups of 8)
    asm("v_permlane32_swap_b32 %0, %1" : "+v"(u0), "+v"(u2));
    asm("v_permlane32_swap_b32 %0, %1" : "+v"(u1), "+v"(u3));
    asm("v_permlane32_swap_b32 %0, %1" : "+v"(u4), "+v"(u6));
    asm("v_permlane32_swap_b32 %0, %1" : "+v"(u5), "+v"(u7));
    U4B p1; p1.u = make_uint4(u0, u1, u2, u3);  // keys kt*32+0..15
    U4B p2; p2.u = make_uint4(u4, u5, u6, u7);  // keys kt*32+16..31
    accPV = __builtin_amdgcn_mfma_f32_32x32x16_bf16(p1.s, bv1.s, accPV, 0, 0, 0);
    accPV = __builtin_amdgcn_mfma_f32_32x32x16_bf16(p2.s, bv2.s, accPV, 0, 0, 0);
  }

  // Epilogue: D_pv[query row][col]: col 0-2 = o, col 3 = l. Normalize + write.
  int base3 = (lane & 32) | 3;
  float inv[16];
#pragma unroll
  for (int rg = 0; rg < 16; ++rg)
    inv[rg] = __shfl(fast_rcp(accPV[rg]), base3, 64);
  if (col < 3) {
#pragma unroll
    for (int rg = 0; rg < 16; ++rg) {
      int row = (rg & 3) + 8 * (rg >> 2) + 4 * h32;
      AO[((size_t)(b * SS + q32 + row)) * EE + h * 3 + col] = accPV[rg] * inv[rg];
    }
  }
}

// Output projection: AO (4096 x 192) @ Wo^T -> out. grid = (3, 64).
__global__ __launch_bounds__(256) void gemm_out_k(
    const float* __restrict__ x, const float* __restrict__ Wo, float* __restrict__ out)
{
  __shared__ __align__(16) float xs[64][68];
  __shared__ __align__(16) float wsm[64][68];
  int bx = blockIdx.x;   // 0..2
  int by = blockIdx.y;   // 0..63
  int t = threadIdx.x;
  int colBase = bx * 64;
  int rowBase = by * 64;
  int lrow = t >> 2, lq = t & 3;
  int tr = t & 15, tc = t >> 4;
  float acc[4][4] = {};

  for (int kk = 0; kk < 3; ++kk) {
    const float* xg = x + (size_t)(rowBase + lrow) * EE + kk * 64;
    const float* wg = Wo + (size_t)(colBase + lrow) * EE + kk * 64;
    float4 xv[4], wv[4];
#pragma unroll
    for (int i = 0; i < 4; ++i) {
      xv[i] = ((const float4*)xg)[lq + 4 * i];
      wv[i] = ((const float4*)wg)[lq + 4 * i];
    }
    __syncthreads();
#pragma unroll
    for (int i = 0; i < 4; ++i) {
      int k0 = (lq + 4 * i) * 4;
      xs[k0 + 0][lrow] = xv[i].x; xs[k0 + 1][lrow] = xv[i].y;
      xs[k0 + 2][lrow] = xv[i].z; xs[k0 + 3][lrow] = xv[i].w;
      wsm[k0 + 0][lrow] = wv[i].x; wsm[k0 + 1][lrow] = wv[i].y;
      wsm[k0 + 2][lrow] = wv[i].z; wsm[k0 + 3][lrow] = wv[i].w;
    }
    __syncthreads();
#pragma unroll 8
    for (int k = 0; k < 64; ++k) {
      float4 a = *(const float4*)&xs[k][tr * 4];
      float4 bv = *(const float4*)&wsm[k][tc * 4];
      acc[0][0] += a.x * bv.x; acc[0][1] += a.x * bv.y; acc[0][2] += a.x * bv.z; acc[0][3] += a.x * bv.w;
      acc[1][0] += a.y * bv.x; acc[1][1] += a.y * bv.y; acc[1][2] += a.y * bv.z; acc[1][3] += a.y * bv.w;
      acc[2][0] += a.z * bv.x; acc[2][1] += a.z * bv.y; acc[2][2] += a.z * bv.z; acc[2][3] += a.z * bv.w;
      acc[3][0] += a.w * bv.x; acc[3][1] += a.w * bv.y; acc[3][2] += a.w * bv.z; acc[3][3] += a.w * bv.w;
    }
  }

#pragma unroll
  for (int i = 0; i < 4; ++i) {
    int r = rowBase + tr * 4 + i;
#pragma unroll
    for (int j = 0; j < 4; ++j) {
      int o = colBase + tc * 4 + j;
      out[(size_t)r * EE + o] = acc[i][j];
    }
  }
}

extern "C" void kernel_launch(void* const* d_in, const int* in_sizes, int n_in,
                              void* d_out, int out_size, void* d_ws, size_t ws_size,
                              hipStream_t stream) {
  const float* x   = (const float*)d_in[0];
  const float* Wq  = (const float*)d_in[1];
  const float* Wk  = (const float*)d_in[2];
  const float* Wv  = (const float*)d_in[3];
  const float* Wo  = (const float*)d_in[4];
  const float* rot = (const float*)d_in[5];
  float* ws  = (float*)d_ws;
  float* WqR = ws + OFF_WQR;
  float* WkR = ws + OFF_WKR;
  float* Q   = ws + OFF_Q;
  unsigned short* Kf = (unsigned short*)(ws + OFF_KF);
  unsigned short* Vc = (unsigned short*)(ws + OFF_VC);
  float* AO  = ws + OFF_AO;
  float* out = (float*)d_out;

  fold_rot_k<<<dim3((2 * EE * EE + 255) / 256), 256, 0, stream>>>(Wq, Wk, rot, WqR, WkR);
  gemm_qkv_k<<<dim3(9, 64), 256, 0, stream>>>(x, WqR, WkR, Wv, Q,
                                              (__hip_bfloat16*)Kf, (__hip_bfloat16*)Vc);
  attn_k<<<dim3(BH * 8), 256, 0, stream>>>(Q, Kf, Vc, AO);
  gemm_out_k<<<dim3(3, 64), 256, 0, stream>>>(AO, Wo, out);
}

// Round 8
// 77.383 us; speedup vs baseline: 3.0896x; 1.0015x over previous
//
#include <hip/hip_runtime.h>
#include <hip/hip_bf16.h>

// Problem dims
#define BB 4
#define SS 1024
#define EE 192
#define HH 64
// D = 3 (head dim)

constexpr int BH = BB * HH;  // 256

typedef __attribute__((ext_vector_type(8))) short bs8;    // 8 bf16 = 4 VGPR (MFMA A/B frag)
typedef __attribute__((ext_vector_type(16))) float fx16;  // MFMA C/D frag
union U4B { uint4 u; bs8 s; };

// ws layout (in floats)
constexpr size_t OFF_WQR = 0;                          // E*E rotated+scaled Wq
constexpr size_t OFF_WKR = OFF_WQR + (size_t)EE*EE;    // E*E rotated Wk
constexpr size_t OFF_Q   = OFF_WKR + (size_t)EE*EE;    // (B*H, S, 4) fp32
constexpr size_t OFF_KF  = OFF_Q  + (size_t)BH*SS*4;   // (B*H, S, 4) bf16: k0 k1 k2 0
constexpr size_t OFF_VC  = OFF_KF + (size_t)BH*SS*2;   // (B*H, 3, S) bf16 col-major
constexpr size_t OFF_AO  = OFF_VC + (size_t)BH*SS*3/2; // (B, S, E) fp32

static __device__ __forceinline__ float fast_exp2(float x) {
#if __has_builtin(__builtin_amdgcn_exp2f)
  return __builtin_amdgcn_exp2f(x);
#else
  return exp2f(x);
#endif
}
static __device__ __forceinline__ float fast_rcp(float x) {
#if __has_builtin(__builtin_amdgcn_rcpf)
  return __builtin_amdgcn_rcpf(x);
#else
  return 1.0f / x;
#endif
}

// Fold per-head 3x3 rotation into Wq and Wk (fp32, exact restructuring).
// WqR additionally carries log2(e)/sqrt(3) so attention exp is a single v_exp_f32.
__global__ __launch_bounds__(256) void fold_rot_k(
    const float* __restrict__ Wq, const float* __restrict__ Wk,
    const float* __restrict__ rot, float* __restrict__ WqR, float* __restrict__ WkR)
{
  int t = blockIdx.x * 256 + threadIdx.x;
  if (t >= 2 * EE * EE) return;
  int mat = t / (EE * EE);
  int idx = t % (EE * EE);
  int op = idx / EE, e = idx % EE;      // op = h*3 + e'
  int h = op / 3, ep = op - h * 3;
  const float* W = mat ? Wk : Wq;
  float acc = 0.f;
#pragma unroll
  for (int d = 0; d < 3; ++d)
    acc += rot[h * 9 + d * 3 + ep] * W[(h * 3 + d) * EE + e];
  float scale = mat ? 1.0f : 0.8329876360019913f;  // log2(e)/sqrt(3)
  (mat ? WkR : WqR)[op * EE + e] = acc * scale;
}

// QKV projection GEMM: (4096 x 192) @ W^T for W in {WqR, WkR, Wv}.
// Q -> fp32 (B*H,S,4); K -> bf16 (B*H,S,4) slot3=0; V -> bf16 col-major (B*H,3,S).
__global__ __launch_bounds__(256) void gemm_qkv_k(
    const float* __restrict__ x, const float* __restrict__ WqR,
    const float* __restrict__ WkR, const float* __restrict__ Wv,
    float* __restrict__ Q, __hip_bfloat16* __restrict__ Kf, __hip_bfloat16* __restrict__ Vc)
{
  __shared__ __align__(16) float xs[64][68];
  __shared__ __align__(16) float wsm[64][68];
  int bx = blockIdx.x;   // 0..8
  int by = blockIdx.y;   // 0..63
  int t = threadIdx.x;
  int sel = bx / 3;
  const float* W = (sel == 0) ? WqR : (sel == 1 ? WkR : Wv);
  int colBase = (bx % 3) * 64;
  int rowBase = by * 64;
  int lrow = t >> 2, lq = t & 3;
  int tr = t & 15, tc = t >> 4;
  float acc[4][4] = {};

  for (int kk = 0; kk < 3; ++kk) {
    const float* xg = x + (size_t)(rowBase + lrow) * EE + kk * 64;
    const float* wg = W + (size_t)(colBase + lrow) * EE + kk * 64;
    float4 xv[4], wv[4];
#pragma unroll
    for (int i = 0; i < 4; ++i) {
      xv[i] = ((const float4*)xg)[lq + 4 * i];
      wv[i] = ((const float4*)wg)[lq + 4 * i];
    }
    __syncthreads();
#pragma unroll
    for (int i = 0; i < 4; ++i) {
      int k0 = (lq + 4 * i) * 4;
      xs[k0 + 0][lrow] = xv[i].x; xs[k0 + 1][lrow] = xv[i].y;
      xs[k0 + 2][lrow] = xv[i].z; xs[k0 + 3][lrow] = xv[i].w;
      wsm[k0 + 0][lrow] = wv[i].x; wsm[k0 + 1][lrow] = wv[i].y;
      wsm[k0 + 2][lrow] = wv[i].z; wsm[k0 + 3][lrow] = wv[i].w;
    }
    __syncthreads();
#pragma unroll 8
    for (int k = 0; k < 64; ++k) {
      float4 a = *(const float4*)&xs[k][tr * 4];
      float4 bv = *(const float4*)&wsm[k][tc * 4];
      acc[0][0] += a.x * bv.x; acc[0][1] += a.x * bv.y; acc[0][2] += a.x * bv.z; acc[0][3] += a.x * bv.w;
      acc[1][0] += a.y * bv.x; acc[1][1] += a.y * bv.y; acc[1][2] += a.y * bv.z; acc[1][3] += a.y * bv.w;
      acc[2][0] += a.z * bv.x; acc[2][1] += a.z * bv.y; acc[2][2] += a.z * bv.z; acc[2][3] += a.z * bv.w;
      acc[3][0] += a.w * bv.x; acc[3][1] += a.w * bv.y; acc[3][2] += a.w * bv.z; acc[3][3] += a.w * bv.w;
    }
  }

#pragma unroll
  for (int i = 0; i < 4; ++i) {
    int r = rowBase + tr * 4 + i;
    int b = r >> 10, s = r & (SS - 1);
#pragma unroll
    for (int j = 0; j < 4; ++j) {
      int o = colBase + tc * 4 + j;
      int h = o / 3, d = o - h * 3;
      size_t bh = (size_t)(b * HH + h);
      if (sel == 0) {
        Q[(bh * SS + s) * 4 + d] = acc[i][j];
      } else if (sel == 1) {
        Kf[(bh * SS + s) * 4 + d] = __float2bfloat16(acc[i][j]);
        if (d == 2) Kf[(bh * SS + s) * 4 + 3] = __float2bfloat16(0.0f);  // finite pad for A-frag
      } else {
        Vc[bh * (3 * SS) + (size_t)d * SS + s] = __float2bfloat16(acc[i][j]);
      }
    }
  }
}

// MFMA attention. Block = (head, query-eighth): 2048 blocks. launch_bounds
// (256,4): 128-reg budget so the QK MFMA result S lives in VGPRs (exp/cvt are
// VALU-only; at (256,8) regalloc forced S into AGPRs -> 32 accvgpr moves/kt,
// the r7 "mystery VALU"). Swapped QK^T (A=K, B=Q) -> D[key][query]; B(=Q)
// zero for k>=3 so K is (S,4) bf16 and the A-frag is {k-pair,0,0}.
// exp2 in-register, cvt_pk + permlane32_swap -> PV A-frags; V ones-column
// yields l via the PV MFMA.
__global__ __launch_bounds__(256, 4) void attn_k(
    const float* __restrict__ Qw, const unsigned short* __restrict__ Kfg,
    const unsigned short* __restrict__ Vcg, float* __restrict__ AO)
{
  __shared__ __align__(16) short KfL[1024 * 4];   // 8 KB: [key][k0 k1 k2 0]
  __shared__ __align__(16) short VcL[4 * 1040];   // 8.1 KB: rows v0 v1 v2 ones
  int bh = blockIdx.x & 255;       // eighth-major: same-head blocks 256 apart (same XCD)
  int eighth = blockIdx.x >> 8;
  int b = bh >> 6, h = bh & 63;

  // stage K: plain uint2 copy (slot3 already zero from gemm)
  const uint2* ksrc = (const uint2*)Kfg + (size_t)bh * 1024;
  uint2* kdst = (uint2*)KfL;
  for (int i = threadIdx.x; i < 1024; i += 256) kdst[i] = ksrc[i];
  // stage V rows 0-2; row 3 = bf16(1.0) ones, generated locally
  const uint4* vsrc = (const uint4*)Vcg + (size_t)bh * 384;
  for (int i = threadIdx.x; i < 384; i += 256) {
    int r = i >> 7, cq = i & 127;
    *(uint4*)(VcL + r * 1040 + cq * 8) = vsrc[i];
  }
  {
    unsigned v1 = 0x3F803F80u;
    for (int i = threadIdx.x; i < 128; i += 256)
      *(uint4*)(VcL + 3 * 1040 + i * 8) = make_uint4(v1, v1, v1, v1);
  }
  __syncthreads();

  int lane = threadIdx.x & 63, w = threadIdx.x >> 6;
  int h32 = lane >> 5;          // lane half
  int col = lane & 31;          // query (B col) / key (A row)
  int q32 = eighth * 128 + w * 32;

  // Q B-frag (h1 lanes = zero half of K-dim; k=3..7 zero)
  float4 qv = *(const float4*)&Qw[((size_t)bh * SS + q32 + col) * 4];
  unsigned pa, pb;
  asm("v_cvt_pk_bf16_f32 %0, %1, %2" : "=v"(pa) : "v"(qv.x), "v"(qv.y));
  asm("v_cvt_pk_bf16_f32 %0, %1, %2" : "=v"(pb) : "v"(qv.z), "v"(0.0f));
  U4B bq; bq.u = make_uint4(h32 ? 0u : pa, h32 ? 0u : pb, 0u, 0u);

  const fx16 zc = {0,0,0,0, 0,0,0,0, 0,0,0,0, 0,0,0,0};
  fx16 accPV = zc;
  int vbase = (col & 3) * 1040 + 8 * h32;

  for (int kt = 0; kt < 32; ++kt) {
    // K A-frag: all lanes read key kt*32+col (h1 = broadcast copy; its k-slots
    // multiply B=0). uint2 -> regs 0-1, regs 2-3 = 0.
    uint2 kk = *(const uint2*)(KfL + (size_t)(kt * 32 + col) * 4);
    U4B ak; ak.u = make_uint4(kk.x, kk.y, 0u, 0u);
    // V B-frags (keys kt*32+0..15 and +16..31), col&3 selects v0/v1/v2/ones
    U4B bv1; bv1.u = *(const uint4*)(VcL + vbase + kt * 32);
    U4B bv2; bv2.u = *(const uint4*)(VcL + vbase + kt * 32 + 16);

    fx16 S = __builtin_amdgcn_mfma_f32_32x32x16_bf16(ak.s, bq.s, zc, 0, 0, 0);
    asm("" : "+v"(S));   // pin S to VGPR class (exp/cvt consumers are VALU-only)
#pragma unroll
    for (int i = 0; i < 16; ++i) S[i] = fast_exp2(S[i]);  // P (log2e/sqrt3 in Q)
    unsigned u0, u1, u2, u3, u4, u5, u6, u7;
    asm("v_cvt_pk_bf16_f32 %0, %1, %2" : "=v"(u0) : "v"(S[0]),  "v"(S[1]));
    asm("v_cvt_pk_bf16_f32 %0, %1, %2" : "=v"(u1) : "v"(S[2]),  "v"(S[3]));
    asm("v_cvt_pk_bf16_f32 %0, %1, %2" : "=v"(u2) : "v"(S[4]),  "v"(S[5]));
    asm("v_cvt_pk_bf16_f32 %0, %1, %2" : "=v"(u3) : "v"(S[6]),  "v"(S[7]));
    asm("v_cvt_pk_bf16_f32 %0, %1, %2" : "=v"(u4) : "v"(S[8]),  "v"(S[9]));
    asm("v_cvt_pk_bf16_f32 %0, %1, %2" : "=v"(u5) : "v"(S[10]), "v"(S[11]));
    asm("v_cvt_pk_bf16_f32 %0, %1, %2" : "=v"(u6) : "v"(S[12]), "v"(S[13]));
    asm("v_cvt_pk_bf16_f32 %0, %1, %2" : "=v"(u7) : "v"(S[14]), "v"(S[15]));
    // redistribute D-layout (key groups of 4) -> A-frag (key groups of 8)
    asm("v_permlane32_swap_b32 %0, %1" : "+v"(u0), "+v"(u2));
    asm("v_permlane32_swap_b32 %0, %1" : "+v"(u1), "+v"(u3));
    asm("v_permlane32_swap_b32 %0, %1" : "+v"(u4), "+v"(u6));
    asm("v_permlane32_swap_b32 %0, %1" : "+v"(u5), "+v"(u7));
    U4B p1; p1.u = make_uint4(u0, u1, u2, u3);  // keys kt*32+0..15
    U4B p2; p2.u = make_uint4(u4, u5, u6, u7);  // keys kt*32+16..31
    accPV = __builtin_amdgcn_mfma_f32_32x32x16_bf16(p1.s, bv1.s, accPV, 0, 0, 0);
    accPV = __builtin_amdgcn_mfma_f32_32x32x16_bf16(p2.s, bv2.s, accPV, 0, 0, 0);
  }

  // Epilogue: D_pv[query row][col]: col 0-2 = o, col 3 = l. Normalize + write.
  int base3 = (lane & 32) | 3;
  float inv[16];
#pragma unroll
  for (int rg = 0; rg < 16; ++rg)
    inv[rg] = __shfl(fast_rcp(accPV[rg]), base3, 64);
  if (col < 3) {
#pragma unroll
    for (int rg = 0; rg < 16; ++rg) {
      int row = (rg & 3) + 8 * (rg >> 2) + 4 * h32;
      AO[((size_t)(b * SS + q32 + row)) * EE + h * 3 + col] = accPV[rg] * inv[rg];
    }
  }
}

// Output projection: AO (4096 x 192) @ Wo^T -> out. grid = (3, 64).
__global__ __launch_bounds__(256) void gemm_out_k(
    const float* __restrict__ x, const float* __restrict__ Wo, float* __restrict__ out)
{
  __shared__ __align__(16) float xs[64][68];
  __shared__ __align__(16) float wsm[64][68];
  int bx = blockIdx.x;   // 0..2
  int by = blockIdx.y;   // 0..63
  int t = threadIdx.x;
  int colBase = bx * 64;
  int rowBase = by * 64;
  int lrow = t >> 2, lq = t & 3;
  int tr = t & 15, tc = t >> 4;
  float acc[4][4] = {};

  for (int kk = 0; kk < 3; ++kk) {
    const float* xg = x + (size_t)(rowBase + lrow) * EE + kk * 64;
    const float* wg = Wo + (size_t)(colBase + lrow) * EE + kk * 64;
    float4 xv[4], wv[4];
#pragma unroll
    for (int i = 0; i < 4; ++i) {
      xv[i] = ((const float4*)xg)[lq + 4 * i];
      wv[i] = ((const float4*)wg)[lq + 4 * i];
    }
    __syncthreads();
#pragma unroll
    for (int i = 0; i < 4; ++i) {
      int k0 = (lq + 4 * i) * 4;
      xs[k0 + 0][lrow] = xv[i].x; xs[k0 + 1][lrow] = xv[i].y;
      xs[k0 + 2][lrow] = xv[i].z; xs[k0 + 3][lrow] = xv[i].w;
      wsm[k0 + 0][lrow] = wv[i].x; wsm[k0 + 1][lrow] = wv[i].y;
      wsm[k0 + 2][lrow] = wv[i].z; wsm[k0 + 3][lrow] = wv[i].w;
    }
    __syncthreads();
#pragma unroll 8
    for (int k = 0; k < 64; ++k) {
      float4 a = *(const float4*)&xs[k][tr * 4];
      float4 bv = *(const float4*)&wsm[k][tc * 4];
      acc[0][0] += a.x * bv.x; acc[0][1] += a.x * bv.y; acc[0][2] += a.x * bv.z; acc[0][3] += a.x * bv.w;
      acc[1][0] += a.y * bv.x; acc[1][1] += a.y * bv.y; acc[1][2] += a.y * bv.z; acc[1][3] += a.y * bv.w;
      acc[2][0] += a.z * bv.x; acc[2][1] += a.z * bv.y; acc[2][2] += a.z * bv.z; acc[2][3] += a.z * bv.w;
      acc[3][0] += a.w * bv.x; acc[3][1] += a.w * bv.y; acc[3][2] += a.w * bv.z; acc[3][3] += a.w * bv.w;
    }
  }

#pragma unroll
  for (int i = 0; i < 4; ++i) {
    int r = rowBase + tr * 4 + i;
#pragma unroll
    for (int j = 0; j < 4; ++j) {
      int o = colBase + tc * 4 + j;
      out[(size_t)r * EE + o] = acc[i][j];
    }
  }
}

extern "C" void kernel_launch(void* const* d_in, const int* in_sizes, int n_in,
                              void* d_out, int out_size, void* d_ws, size_t ws_size,
                              hipStream_t stream) {
  const float* x   = (const float*)d_in[0];
  const float* Wq  = (const float*)d_in[1];
  const float* Wk  = (const float*)d_in[2];
  const float* Wv  = (const float*)d_in[3];
  const float* Wo  = (const float*)d_in[4];
  const float* rot = (const float*)d_in[5];
  float* ws  = (float*)d_ws;
  float* WqR = ws + OFF_WQR;
  float* WkR = ws + OFF_WKR;
  float* Q   = ws + OFF_Q;
  unsigned short* Kf = (unsigned short*)(ws + OFF_KF);
  unsigned short* Vc = (unsigned short*)(ws + OFF_VC);
  float* AO  = ws + OFF_AO;
  float* out = (float*)d_out;

  fold_rot_k<<<dim3((2 * EE * EE + 255) / 256), 256, 0, stream>>>(Wq, Wk, rot, WqR, WkR);
  gemm_qkv_k<<<dim3(9, 64), 256, 0, stream>>>(x, WqR, WkR, Wv, Q,
                                              (__hip_bfloat16*)Kf, (__hip_bfloat16*)Vc);
  attn_k<<<dim3(BH * 8), 256, 0, stream>>>(Q, Kf, Vc, AO);
  gemm_out_k<<<dim3(3, 64), 256, 0, stream>>>(AO, Wo, out);
}

// Round 9
// 63.852 us; speedup vs baseline: 3.7444x; 1.2119x over previous
//
#include <hip/hip_runtime.h>
#include <hip/hip_bf16.h>

// Problem dims
#define BB 4
#define SS 1024
#define EE 192
#define HH 64
// D = 3 (head dim)

constexpr int BH = BB * HH;  // 256

typedef __attribute__((ext_vector_type(8))) short bs8;    // 8 bf16 = 4 VGPR (MFMA A/B frag)
typedef __attribute__((ext_vector_type(16))) float fx16;  // MFMA C/D frag
union U4B { uint4 u; bs8 s; };

// ws layout (float units)
constexpr size_t OFF_Q   = 0;                            // (B*H,S,4) fp32
constexpr size_t OFF_KF  = OFF_Q  + (size_t)BH*SS*4;     // (B*H,S,4) bf16: k0 k1 k2 0
constexpr size_t OFF_VC  = OFF_KF + (size_t)BH*SS*2;     // (B*H,3,S) bf16 col-major
constexpr size_t OFF_AO  = OFF_VC + (size_t)BH*SS*3/2;   // (B,S,E) fp32
constexpr size_t OFF_WCH = OFF_AO + (size_t)BB*SS*EE;    // (576,192) bf16 hi (WqR|WkR|Wv)
constexpr size_t OFF_WCL = OFF_WCH + (size_t)576*EE/2;   // lo
constexpr size_t OFF_WOH = OFF_WCL + (size_t)576*EE/2;   // (192,192) bf16 hi (Wo)
constexpr size_t OFF_WOL = OFF_WOH + (size_t)EE*EE/2;    // lo

static __device__ __forceinline__ float fast_exp2(float x) {
#if __has_builtin(__builtin_amdgcn_exp2f)
  return __builtin_amdgcn_exp2f(x);
#else
  return exp2f(x);
#endif
}
static __device__ __forceinline__ float fast_rcp(float x) {
#if __has_builtin(__builtin_amdgcn_rcpf)
  return __builtin_amdgcn_rcpf(x);
#else
  return 1.0f / x;
#endif
}

// split a pair of fp32 into packed bf16 hi + bf16 lo (lo = residual)
static __device__ __forceinline__ void split2(float a, float b, unsigned& hi, unsigned& lo) {
  unsigned h;
  asm("v_cvt_pk_bf16_f32 %0, %1, %2" : "=v"(h) : "v"(a), "v"(b));
  float ha = __uint_as_float(h << 16);
  float hb = __uint_as_float(h & 0xFFFF0000u);
  float la = a - ha, lb = b - hb;
  unsigned l;
  asm("v_cvt_pk_bf16_f32 %0, %1, %2" : "=v"(l) : "v"(la), "v"(lb));
  hi = h; lo = l;
}

// Weight prep: fold per-head 3x3 rotation into Wq (with log2e/sqrt(3) scale)
// and Wk (fp32, exact), concat [WqR|WkR|Wv] as 576x192, split every matrix
// (incl. Wo) into bf16 hi + lo residual for split-bf16 MFMA GEMMs.
__global__ __launch_bounds__(256) void fold_split_k(
    const float* __restrict__ Wq, const float* __restrict__ Wk,
    const float* __restrict__ Wv, const float* __restrict__ Wo,
    const float* __restrict__ rot,
    __hip_bfloat16* __restrict__ Wch, __hip_bfloat16* __restrict__ Wcl,
    __hip_bfloat16* __restrict__ Woh, __hip_bfloat16* __restrict__ Wol)
{
  int t = blockIdx.x * 256 + threadIdx.x;
  float val;
  __hip_bfloat16 *ph, *pl;
  int idx;
  if (t < 576 * EE) {
    int o = t / EE, e = t - o * EE;
    int s3 = o / 192, oo = o - s3 * 192;
    int h = oo / 3, ep = oo - h * 3;
    if (s3 == 2) {
      val = Wv[(size_t)oo * EE + e];
    } else {
      const float* W = s3 ? Wk : Wq;
      float acc = 0.f;
#pragma unroll
      for (int d = 0; d < 3; ++d)
        acc += rot[h * 9 + d * 3 + ep] * W[(size_t)(h * 3 + d) * EE + e];
      val = acc * (s3 ? 1.0f : 0.8329876360019913f);  // log2(e)/sqrt(3) for Q
    }
    ph = Wch; pl = Wcl; idx = t;
  } else {
    int u = t - 576 * EE;
    if (u >= EE * EE) return;
    val = Wo[u]; ph = Woh; pl = Wol; idx = u;
  }
  __hip_bfloat16 hi = __float2bfloat16(val);
  float lo = val - __bfloat162float(hi);
  ph[idx] = hi;
  pl[idx] = __float2bfloat16(lo);
}

// QKV projection, split-bf16 MFMA: C(4096x576) = x(4096x192) @ Wcat^T.
// Block = 64x64 output tile, 4 waves (2x2 of 32x32), K chunked by 64.
// acc = Ah*Bh + Al*Bh + Ah*Bl (lo*lo dropped, ~2^-18) -> fp32-grade result.
__global__ __launch_bounds__(256) void gemm_qkv_k(
    const float* __restrict__ x,
    const unsigned short* __restrict__ Wch, const unsigned short* __restrict__ Wcl,
    float* __restrict__ Q, __hip_bfloat16* __restrict__ Kf, __hip_bfloat16* __restrict__ Vc)
{
  __shared__ __align__(16) short xh[64][72], xl[64][72];
  __shared__ __align__(16) short wh[64][72], wl[64][72];
  int colBase = blockIdx.x * 64;   // col-group over 576 outs
  int rowBase = blockIdx.y * 64;   // row-group over 4096 rows
  int t = threadIdx.x;
  int lane = t & 63, w = t >> 6;
  int wr = w >> 1, wc = w & 1;
  int l31 = lane & 31, lh = lane >> 5;

  const fx16 zc = {0,0,0,0, 0,0,0,0, 0,0,0,0, 0,0,0,0};
  fx16 acc = zc;

  int srow = t >> 2, sk = (t & 3) * 16;

  for (int kk = 0; kk < 3; ++kk) {
    const float4* xg = (const float4*)&x[(size_t)(rowBase + srow) * EE + kk * 64 + sk];
    float4 v0 = xg[0], v1 = xg[1], v2 = xg[2], v3 = xg[3];
    const uint4* whg = (const uint4*)&Wch[(size_t)(colBase + srow) * EE + kk * 64 + sk];
    const uint4* wlg = (const uint4*)&Wcl[(size_t)(colBase + srow) * EE + kk * 64 + sk];
    uint4 wh0 = whg[0], wh1 = whg[1], wl0 = wlg[0], wl1 = wlg[1];

    unsigned hu[8], lu[8];
    split2(v0.x, v0.y, hu[0], lu[0]); split2(v0.z, v0.w, hu[1], lu[1]);
    split2(v1.x, v1.y, hu[2], lu[2]); split2(v1.z, v1.w, hu[3], lu[3]);
    split2(v2.x, v2.y, hu[4], lu[4]); split2(v2.z, v2.w, hu[5], lu[5]);
    split2(v3.x, v3.y, hu[6], lu[6]); split2(v3.z, v3.w, hu[7], lu[7]);

    __syncthreads();  // previous chunk's MFMA reads complete
    *(uint4*)&xh[srow][sk]     = make_uint4(hu[0], hu[1], hu[2], hu[3]);
    *(uint4*)&xh[srow][sk + 8] = make_uint4(hu[4], hu[5], hu[6], hu[7]);
    *(uint4*)&xl[srow][sk]     = make_uint4(lu[0], lu[1], lu[2], lu[3]);
    *(uint4*)&xl[srow][sk + 8] = make_uint4(lu[4], lu[5], lu[6], lu[7]);
    *(uint4*)&wh[srow][sk]     = wh0;
    *(uint4*)&wh[srow][sk + 8] = wh1;
    *(uint4*)&wl[srow][sk]     = wl0;
    *(uint4*)&wl[srow][sk + 8] = wl1;
    __syncthreads();

#pragma unroll
    for (int ks = 0; ks < 4; ++ks) {
      int ac = ks * 16 + lh * 8;
      U4B Ah, Al, Bh, Bl;
      Ah.u = *(const uint4*)&xh[wr * 32 + l31][ac];
      Al.u = *(const uint4*)&xl[wr * 32 + l31][ac];
      Bh.u = *(const uint4*)&wh[wc * 32 + l31][ac];
      Bl.u = *(const uint4*)&wl[wc * 32 + l31][ac];
      acc = __builtin_amdgcn_mfma_f32_32x32x16_bf16(Ah.s, Bh.s, acc, 0, 0, 0);
      acc = __builtin_amdgcn_mfma_f32_32x32x16_bf16(Al.s, Bh.s, acc, 0, 0, 0);
      acc = __builtin_amdgcn_mfma_f32_32x32x16_bf16(Ah.s, Bl.s, acc, 0, 0, 0);
    }
  }

  // epilogue: C/D layout col=l31, row=(r&3)+8*(r>>2)+4*lh
  int o = colBase + wc * 32 + l31;
  int s3 = o / 192, oo = o - s3 * 192;
  int hh = oo / 3, d = oo - hh * 3;
#pragma unroll
  for (int r = 0; r < 16; ++r) {
    int row = rowBase + wr * 32 + (r & 3) + 8 * (r >> 2) + 4 * lh;
    int b = row >> 10, s = row & (SS - 1);
    size_t bh = (size_t)(b * HH + hh);
    float v = acc[r];
    if (s3 == 0) {
      Q[(bh * SS + s) * 4 + d] = v;
    } else if (s3 == 1) {
      Kf[(bh * SS + s) * 4 + d] = __float2bfloat16(v);
      if (d == 2) Kf[(bh * SS + s) * 4 + 3] = __float2bfloat16(0.0f);
    } else {
      Vc[bh * (3 * SS) + (size_t)d * SS + s] = __float2bfloat16(v);
    }
  }
}

// MFMA attention (unchanged from r7/r8). Block = (head, query-eighth).
__global__ __launch_bounds__(256, 4) void attn_k(
    const float* __restrict__ Qw, const unsigned short* __restrict__ Kfg,
    const unsigned short* __restrict__ Vcg, float* __restrict__ AO)
{
  __shared__ __align__(16) short KfL[1024 * 4];   // 8 KB: [key][k0 k1 k2 0]
  __shared__ __align__(16) short VcL[4 * 1040];   // 8.1 KB: rows v0 v1 v2 ones
  int bh = blockIdx.x & 255;       // eighth-major: same-head blocks 256 apart (same XCD)
  int eighth = blockIdx.x >> 8;
  int b = bh >> 6, h = bh & 63;

  const uint2* ksrc = (const uint2*)Kfg + (size_t)bh * 1024;
  uint2* kdst = (uint2*)KfL;
  for (int i = threadIdx.x; i < 1024; i += 256) kdst[i] = ksrc[i];
  const uint4* vsrc = (const uint4*)Vcg + (size_t)bh * 384;
  for (int i = threadIdx.x; i < 384; i += 256) {
    int r = i >> 7, cq = i & 127;
    *(uint4*)(VcL + r * 1040 + cq * 8) = vsrc[i];
  }
  {
    unsigned v1 = 0x3F803F80u;
    for (int i = threadIdx.x; i < 128; i += 256)
      *(uint4*)(VcL + 3 * 1040 + i * 8) = make_uint4(v1, v1, v1, v1);
  }
  __syncthreads();

  int lane = threadIdx.x & 63, w = threadIdx.x >> 6;
  int h32 = lane >> 5;
  int col = lane & 31;
  int q32 = eighth * 128 + w * 32;

  float4 qv = *(const float4*)&Qw[((size_t)bh * SS + q32 + col) * 4];
  unsigned pa, pb;
  asm("v_cvt_pk_bf16_f32 %0, %1, %2" : "=v"(pa) : "v"(qv.x), "v"(qv.y));
  asm("v_cvt_pk_bf16_f32 %0, %1, %2" : "=v"(pb) : "v"(qv.z), "v"(0.0f));
  U4B bq; bq.u = make_uint4(h32 ? 0u : pa, h32 ? 0u : pb, 0u, 0u);

  const fx16 zc = {0,0,0,0, 0,0,0,0, 0,0,0,0, 0,0,0,0};
  fx16 accPV = zc;
  int vbase = (col & 3) * 1040 + 8 * h32;

  for (int kt = 0; kt < 32; ++kt) {
    uint2 kk = *(const uint2*)(KfL + (size_t)(kt * 32 + col) * 4);
    U4B ak; ak.u = make_uint4(kk.x, kk.y, 0u, 0u);
    U4B bv1; bv1.u = *(const uint4*)(VcL + vbase + kt * 32);
    U4B bv2; bv2.u = *(const uint4*)(VcL + vbase + kt * 32 + 16);

    fx16 S = __builtin_amdgcn_mfma_f32_32x32x16_bf16(ak.s, bq.s, zc, 0, 0, 0);
    asm("" : "+v"(S));
#pragma unroll
    for (int i = 0; i < 16; ++i) S[i] = fast_exp2(S[i]);
    unsigned u0, u1, u2, u3, u4, u5, u6, u7;
    asm("v_cvt_pk_bf16_f32 %0, %1, %2" : "=v"(u0) : "v"(S[0]),  "v"(S[1]));
    asm("v_cvt_pk_bf16_f32 %0, %1, %2" : "=v"(u1) : "v"(S[2]),  "v"(S[3]));
    asm("v_cvt_pk_bf16_f32 %0, %1, %2" : "=v"(u2) : "v"(S[4]),  "v"(S[5]));
    asm("v_cvt_pk_bf16_f32 %0, %1, %2" : "=v"(u3) : "v"(S[6]),  "v"(S[7]));
    asm("v_cvt_pk_bf16_f32 %0, %1, %2" : "=v"(u4) : "v"(S[8]),  "v"(S[9]));
    asm("v_cvt_pk_bf16_f32 %0, %1, %2" : "=v"(u5) : "v"(S[10]), "v"(S[11]));
    asm("v_cvt_pk_bf16_f32 %0, %1, %2" : "=v"(u6) : "v"(S[12]), "v"(S[13]));
    asm("v_cvt_pk_bf16_f32 %0, %1, %2" : "=v"(u7) : "v"(S[14]), "v"(S[15]));
    asm("v_permlane32_swap_b32 %0, %1" : "+v"(u0), "+v"(u2));
    asm("v_permlane32_swap_b32 %0, %1" : "+v"(u1), "+v"(u3));
    asm("v_permlane32_swap_b32 %0, %1" : "+v"(u4), "+v"(u6));
    asm("v_permlane32_swap_b32 %0, %1" : "+v"(u5), "+v"(u7));
    U4B p1; p1.u = make_uint4(u0, u1, u2, u3);
    U4B p2; p2.u = make_uint4(u4, u5, u6, u7);
    accPV = __builtin_amdgcn_mfma_f32_32x32x16_bf16(p1.s, bv1.s, accPV, 0, 0, 0);
    accPV = __builtin_amdgcn_mfma_f32_32x32x16_bf16(p2.s, bv2.s, accPV, 0, 0, 0);
  }

  int base3 = (lane & 32) | 3;
  float inv[16];
#pragma unroll
  for (int rg = 0; rg < 16; ++rg)
    inv[rg] = __shfl(fast_rcp(accPV[rg]), base3, 64);
  if (col < 3) {
#pragma unroll
    for (int rg = 0; rg < 16; ++rg) {
      int row = (rg & 3) + 8 * (rg >> 2) + 4 * h32;
      AO[((size_t)(b * SS + q32 + row)) * EE + h * 3 + col] = accPV[rg] * inv[rg];
    }
  }
}

// Output projection, split-bf16 MFMA: out(4096x192) = AO @ Wo^T. grid (3,64).
__global__ __launch_bounds__(256) void gemm_out_k(
    const float* __restrict__ AO,
    const unsigned short* __restrict__ Woh, const unsigned short* __restrict__ Wol,
    float* __restrict__ out)
{
  __shared__ __align__(16) short xh[64][72], xl[64][72];
  __shared__ __align__(16) short wh[64][72], wl[64][72];
  int colBase = blockIdx.x * 64;
  int rowBase = blockIdx.y * 64;
  int t = threadIdx.x;
  int lane = t & 63, w = t >> 6;
  int wr = w >> 1, wc = w & 1;
  int l31 = lane & 31, lh = lane >> 5;

  const fx16 zc = {0,0,0,0, 0,0,0,0, 0,0,0,0, 0,0,0,0};
  fx16 acc = zc;

  int srow = t >> 2, sk = (t & 3) * 16;

  for (int kk = 0; kk < 3; ++kk) {
    const float4* xg = (const float4*)&AO[(size_t)(rowBase + srow) * EE + kk * 64 + sk];
    float4 v0 = xg[0], v1 = xg[1], v2 = xg[2], v3 = xg[3];
    const uint4* whg = (const uint4*)&Woh[(size_t)(colBase + srow) * EE + kk * 64 + sk];
    const uint4* wlg = (const uint4*)&Wol[(size_t)(colBase + srow) * EE + kk * 64 + sk];
    uint4 wh0 = whg[0], wh1 = whg[1], wl0 = wlg[0], wl1 = wlg[1];

    unsigned hu[8], lu[8];
    split2(v0.x, v0.y, hu[0], lu[0]); split2(v0.z, v0.w, hu[1], lu[1]);
    split2(v1.x, v1.y, hu[2], lu[2]); split2(v1.z, v1.w, hu[3], lu[3]);
    split2(v2.x, v2.y, hu[4], lu[4]); split2(v2.z, v2.w, hu[5], lu[5]);
    split2(v3.x, v3.y, hu[6], lu[6]); split2(v3.z, v3.w, hu[7], lu[7]);

    __syncthreads();
    *(uint4*)&xh[srow][sk]     = make_uint4(hu[0], hu[1], hu[2], hu[3]);
    *(uint4*)&xh[srow][sk + 8] = make_uint4(hu[4], hu[5], hu[6], hu[7]);
    *(uint4*)&xl[srow][sk]     = make_uint4(lu[0], lu[1], lu[2], lu[3]);
    *(uint4*)&xl[srow][sk + 8] = make_uint4(lu[4], lu[5], lu[6], lu[7]);
    *(uint4*)&wh[srow][sk]     = wh0;
    *(uint4*)&wh[srow][sk + 8] = wh1;
    *(uint4*)&wl[srow][sk]     = wl0;
    *(uint4*)&wl[srow][sk + 8] = wl1;
    __syncthreads();

#pragma unroll
    for (int ks = 0; ks < 4; ++ks) {
      int ac = ks * 16 + lh * 8;
      U4B Ah, Al, Bh, Bl;
      Ah.u = *(const uint4*)&xh[wr * 32 + l31][ac];
      Al.u = *(const uint4*)&xl[wr * 32 + l31][ac];
      Bh.u = *(const uint4*)&wh[wc * 32 + l31][ac];
      Bl.u = *(const uint4*)&wl[wc * 32 + l31][ac];
      acc = __builtin_amdgcn_mfma_f32_32x32x16_bf16(Ah.s, Bh.s, acc, 0, 0, 0);
      acc = __builtin_amdgcn_mfma_f32_32x32x16_bf16(Al.s, Bh.s, acc, 0, 0, 0);
      acc = __builtin_amdgcn_mfma_f32_32x32x16_bf16(Ah.s, Bl.s, acc, 0, 0, 0);
    }
  }

  int o = colBase + wc * 32 + l31;
#pragma unroll
  for (int r = 0; r < 16; ++r) {
    int row = rowBase + wr * 32 + (r & 3) + 8 * (r >> 2) + 4 * lh;
    out[(size_t)row * EE + o] = acc[r];
  }
}

extern "C" void kernel_launch(void* const* d_in, const int* in_sizes, int n_in,
                              void* d_out, int out_size, void* d_ws, size_t ws_size,
                              hipStream_t stream) {
  const float* x   = (const float*)d_in[0];
  const float* Wq  = (const float*)d_in[1];
  const float* Wk  = (const float*)d_in[2];
  const float* Wv  = (const float*)d_in[3];
  const float* Wo  = (const float*)d_in[4];
  const float* rot = (const float*)d_in[5];
  float* ws  = (float*)d_ws;
  float* Q   = ws + OFF_Q;
  unsigned short* Kf  = (unsigned short*)(ws + OFF_KF);
  unsigned short* Vc  = (unsigned short*)(ws + OFF_VC);
  float* AO  = ws + OFF_AO;
  unsigned short* Wch = (unsigned short*)(ws + OFF_WCH);
  unsigned short* Wcl = (unsigned short*)(ws + OFF_WCL);
  unsigned short* Woh = (unsigned short*)(ws + OFF_WOH);
  unsigned short* Wol = (unsigned short*)(ws + OFF_WOL);
  float* out = (float*)d_out;

  fold_split_k<<<dim3((576 * EE + EE * EE) / 256), 256, 0, stream>>>(
      Wq, Wk, Wv, Wo, rot,
      (__hip_bfloat16*)Wch, (__hip_bfloat16*)Wcl,
      (__hip_bfloat16*)Woh, (__hip_bfloat16*)Wol);
  gemm_qkv_k<<<dim3(9, 64), 256, 0, stream>>>(x, Wch, Wcl, Q,
                                              (__hip_bfloat16*)Kf, (__hip_bfloat16*)Vc);
  attn_k<<<dim3(BH * 8), 256, 0, stream>>>(Q, Kf, Vc, AO);
  gemm_out_k<<<dim3(3, 64), 256, 0, stream>>>(AO, Woh, Wol, out);
}